// Round 1
// baseline (341.830 us; speedup 1.0000x reference)
//
#include <hip/hip_runtime.h>
#include <hip/hip_bf16.h>
#include <stdint.h>

typedef __attribute__((ext_vector_type(8))) short short8;
typedef __attribute__((ext_vector_type(4))) float f32x4;
typedef __hip_bfloat16 bf16;

#define AS1 __attribute__((address_space(1)))
#define AS3 __attribute__((address_space(3)))

__device__ __forceinline__ void gl16(const void* g, void* l) {
  __builtin_amdgcn_global_load_lds((const AS1 unsigned int*)g,
                                   (AS3 unsigned int*)l, 16, 0, 0);
}

__device__ __forceinline__ unsigned short bfbits(float x) {
  union { bf16 b; unsigned short u; } c; c.b = __float2bfloat16(x); return c.u;
}

// ---------------- fp32 -> bf16 convert (vectorized) ----------------
__global__ __launch_bounds__(256) void k_cvt(const float* __restrict__ src,
                                             bf16* __restrict__ dst, int n8) {
  int i = blockIdx.x * blockDim.x + threadIdx.x;
  int stride = gridDim.x * blockDim.x;
  for (; i < n8; i += stride) {
    const float4* p = (const float4*)src + (size_t)i * 2;
    float4 a = p[0], b = p[1];
    bf16 tmp[8];
    tmp[0] = __float2bfloat16(a.x); tmp[1] = __float2bfloat16(a.y);
    tmp[2] = __float2bfloat16(a.z); tmp[3] = __float2bfloat16(a.w);
    tmp[4] = __float2bfloat16(b.x); tmp[5] = __float2bfloat16(b.y);
    tmp[6] = __float2bfloat16(b.z); tmp[7] = __float2bfloat16(b.w);
    *(short8*)(dst + (size_t)i * 8) = *(short8*)tmp;
  }
}

// ---------------- QKV projection GEMM: C = X[16384,1024] * W[1024,1024]^T ----
// 128x128 tile, BK=32, 4 waves (2x2), double-buffered LDS via global_load_lds.
// Epilogue scatters bf16 into [B,H,T,D].
__global__ __launch_bounds__(256) void k_qkv_gemm(
    const bf16* __restrict__ X, const bf16* __restrict__ Wq,
    const bf16* __restrict__ Wk, const bf16* __restrict__ Wv,
    bf16* __restrict__ Q, bf16* __restrict__ K, bf16* __restrict__ V) {
  const int Kd = 1024;
  __shared__ bf16 As[2][128 * 32];
  __shared__ bf16 Bs[2][128 * 32];
  int bid = blockIdx.x;
  int wsel = bid >> 10;        // 0..2 : q,k,v
  int rem = bid & 1023;
  int mt = rem & 127;
  int nt = rem >> 7;
  const bf16* W = (wsel == 0) ? Wq : (wsel == 1) ? Wk : Wv;
  bf16* Dst = (wsel == 0) ? Q : (wsel == 1) ? K : V;
  int tid = threadIdx.x;
  int lane = tid & 63, wid = tid >> 6;
  int l15 = lane & 15, hi = lane >> 4;
  int wm = wid >> 1, wn = wid & 1;
  const bf16* Abase = X + (size_t)mt * 128 * Kd;
  const bf16* Bbase = W + (size_t)nt * 128 * Kd;

  f32x4 acc[4][4];
#pragma unroll
  for (int i = 0; i < 4; i++)
#pragma unroll
    for (int j = 0; j < 4; j++) acc[i][j] = (f32x4){0.f, 0.f, 0.f, 0.f};

  auto stage = [&](int buf, int kk) {
#pragma unroll
    for (int pass = 0; pass < 2; pass++) {
      int p = pass * 256 + tid;
      int row = p >> 2, uc = p & 3;
      gl16(Abase + (size_t)row * Kd + kk * 32 + uc * 8, (char*)(&As[buf][0]) + p * 16);
      gl16(Bbase + (size_t)row * Kd + kk * 32 + uc * 8, (char*)(&Bs[buf][0]) + p * 16);
    }
  };

  stage(0, 0);
  __syncthreads();
  int buf = 0;
  const int nk = Kd / 32;
  for (int kk = 0; kk < nk; kk++) {
    if (kk + 1 < nk) stage(buf ^ 1, kk + 1);
    short8 af[4], bfr[4];
#pragma unroll
    for (int mf = 0; mf < 4; mf++)
      af[mf] = *(const short8*)(&As[buf][(wm * 64 + mf * 16 + l15) * 32 + hi * 8]);
#pragma unroll
    for (int nf = 0; nf < 4; nf++)
      bfr[nf] = *(const short8*)(&Bs[buf][(wn * 64 + nf * 16 + l15) * 32 + hi * 8]);
#pragma unroll
    for (int mf = 0; mf < 4; mf++)
#pragma unroll
      for (int nf = 0; nf < 4; nf++)
        acc[mf][nf] = __builtin_amdgcn_mfma_f32_16x16x32_bf16(af[mf], bfr[nf], acc[mf][nf], 0, 0, 0);
    __syncthreads();
    buf ^= 1;
  }
#pragma unroll
  for (int mf = 0; mf < 4; mf++) {
#pragma unroll
    for (int r = 0; r < 4; r++) {
      int row = mt * 128 + wm * 64 + mf * 16 + hi * 4 + r;  // token in [0,16384)
      int b = row >> 13, t = row & 8191;
#pragma unroll
      for (int nf = 0; nf < 4; nf++) {
        int col = nt * 128 + wn * 64 + nf * 16 + l15;       // channel
        int h = col >> 6, d = col & 63;
        Dst[((size_t)(b * 16 + h) * 8192 + t) * 64 + d] = __float2bfloat16(acc[mf][nf][r]);
      }
    }
  }
}

// ---------------- output projection GEMM: Out = A[16384,1024] * Wo^T (fp32 out)
__global__ __launch_bounds__(256) void k_out_gemm(
    const bf16* __restrict__ A, const bf16* __restrict__ Wo, float* __restrict__ Out) {
  const int Kd = 1024;
  __shared__ bf16 As[2][128 * 32];
  __shared__ bf16 Bs[2][128 * 32];
  int bid = blockIdx.x;
  int mt = bid & 127;
  int nt = bid >> 7;
  int tid = threadIdx.x;
  int lane = tid & 63, wid = tid >> 6;
  int l15 = lane & 15, hi = lane >> 4;
  int wm = wid >> 1, wn = wid & 1;
  const bf16* Abase = A + (size_t)mt * 128 * Kd;
  const bf16* Bbase = Wo + (size_t)nt * 128 * Kd;

  f32x4 acc[4][4];
#pragma unroll
  for (int i = 0; i < 4; i++)
#pragma unroll
    for (int j = 0; j < 4; j++) acc[i][j] = (f32x4){0.f, 0.f, 0.f, 0.f};

  auto stage = [&](int buf, int kk) {
#pragma unroll
    for (int pass = 0; pass < 2; pass++) {
      int p = pass * 256 + tid;
      int row = p >> 2, uc = p & 3;
      gl16(Abase + (size_t)row * Kd + kk * 32 + uc * 8, (char*)(&As[buf][0]) + p * 16);
      gl16(Bbase + (size_t)row * Kd + kk * 32 + uc * 8, (char*)(&Bs[buf][0]) + p * 16);
    }
  };

  stage(0, 0);
  __syncthreads();
  int buf = 0;
  const int nk = Kd / 32;
  for (int kk = 0; kk < nk; kk++) {
    if (kk + 1 < nk) stage(buf ^ 1, kk + 1);
    short8 af[4], bfr[4];
#pragma unroll
    for (int mf = 0; mf < 4; mf++)
      af[mf] = *(const short8*)(&As[buf][(wm * 64 + mf * 16 + l15) * 32 + hi * 8]);
#pragma unroll
    for (int nf = 0; nf < 4; nf++)
      bfr[nf] = *(const short8*)(&Bs[buf][(wn * 64 + nf * 16 + l15) * 32 + hi * 8]);
#pragma unroll
    for (int mf = 0; mf < 4; mf++)
#pragma unroll
      for (int nf = 0; nf < 4; nf++)
        acc[mf][nf] = __builtin_amdgcn_mfma_f32_16x16x32_bf16(af[mf], bfr[nf], acc[mf][nf], 0, 0, 0);
    __syncthreads();
    buf ^= 1;
  }
#pragma unroll
  for (int mf = 0; mf < 4; mf++) {
#pragma unroll
    for (int r = 0; r < 4; r++) {
      int row = mt * 128 + wm * 64 + mf * 16 + hi * 4 + r;
#pragma unroll
      for (int nf = 0; nf < 4; nf++) {
        int col = nt * 128 + wn * 64 + nf * 16 + l15;
        Out[(size_t)row * 1024 + col] = acc[mf][nf][r];
      }
    }
  }
}

// ---------------- V transpose: [B,H,T,D] -> [B,H,D,T] ----------------
__global__ __launch_bounds__(256) void k_vtrans(const bf16* __restrict__ V,
                                                bf16* __restrict__ VT) {
  const int T = 8192;
  __shared__ bf16 tile[64][72];
  int bid = blockIdx.x;
  int tb = bid & 127;
  int bh = bid >> 7;
  int t0 = tb * 64;
  int tid = threadIdx.x;
  int r = tid >> 2, c4 = tid & 3;
  const bf16* src = V + ((size_t)bh * T + t0 + r) * 64 + c4 * 16;
  short8 a = *(const short8*)src;
  short8 b2 = *(const short8*)(src + 8);
#pragma unroll
  for (int e = 0; e < 8; e++) tile[r][c4 * 16 + e] = ((bf16*)&a)[e];
#pragma unroll
  for (int e = 0; e < 8; e++) tile[r][c4 * 16 + 8 + e] = ((bf16*)&b2)[e];
  __syncthreads();
  alignas(16) bf16 o[16];
#pragma unroll
  for (int e = 0; e < 16; e++) o[e] = tile[c4 * 16 + e][r];
  bf16* dst = VT + ((size_t)bh * 64 + r) * T + t0 + c4 * 16;
  *(short8*)dst = *(short8*)o;
  *(short8*)(dst + 8) = *((short8*)o + 1);
}

// ---------------- sliding-window attention ----------------
// 1 workgroup = 64 queries of one (b,h); 4 waves x 16 q-rows.
// K chunks of 64 keys double-buffered in LDS (XOR-swizzled rows).
// Swapped QK^T: sacc = mfma(K, Q) -> lane holds S[q = lane&15][j = hi*4+r].
__global__ __launch_bounds__(256) void k_attn(
    const bf16* __restrict__ Q, const bf16* __restrict__ K,
    const bf16* __restrict__ VT, bf16* __restrict__ ATT) {
  const int T = 8192;
  __shared__ bf16 Ks[2][64 * 64];
  __shared__ bf16 Vs[2][64 * 64];  // V^T chunk: [d][j]
  __shared__ bf16 Ps[4][16 * 64];  // per-wave P
  int bid = blockIdx.x;
  int qt = bid & 127;
  int bh = bid >> 7;  // 0..31
  int b = bh >> 4, h = bh & 15;
  int tid = threadIdx.x;
  int lane = tid & 63, wid = tid >> 6;
  int l15 = lane & 15, hi = lane >> 4;
  int q0 = qt * 64;
  int qw = q0 + wid * 16;

  // Q fragments (B operand of swapped QK^T): lane holds Q[qw+l15][dh*32+hi*8+e]
  short8 bq[2];
  const bf16* qp = Q + ((size_t)bh * T + qw + l15) * 64 + hi * 8;
  bq[0] = *(const short8*)qp;
  bq[1] = *(const short8*)(qp + 32);

  const bf16* Kbh = K + (size_t)bh * T * 64;
  const bf16* Vbh = VT + (size_t)bh * 64 * T;

  auto stage = [&](int bb, int c0) {
#pragma unroll
    for (int pass = 0; pass < 2; pass++) {
      int p = pass * 256 + tid;
      int row = p >> 3;
      int u = (p & 7) ^ (row & 7);  // inverse-swizzled source (rule 21)
      gl16(Kbh + ((size_t)(c0 + row)) * 64 + u * 8, (char*)(&Ks[bb][0]) + p * 16);
      gl16(Vbh + (size_t)row * T + c0 + u * 8, (char*)(&Vs[bb][0]) + p * 16);
    }
  };

  int cstart = q0 - 512; if (cstart < 0) cstart = 0;
  int nch = (q0 + 64 - cstart) >> 6;

  f32x4 oacc[4];
#pragma unroll
  for (int c = 0; c < 4; c++) oacc[c] = (f32x4){0.f, 0.f, 0.f, 0.f};
  float m = -1e30f, ssum = 0.f;

  stage(0, cstart);
  __syncthreads();
  int buf = 0;
  for (int ci = 0; ci < nch; ci++) {
    int c0 = cstart + (ci << 6);
    if (ci + 1 < nch) stage(buf ^ 1, c0 + 64);
    // QK^T (swapped): A=K chunk rows, B=Q
    f32x4 sacc[4];
#pragma unroll
    for (int ks = 0; ks < 4; ks++) sacc[ks] = (f32x4){0.f, 0.f, 0.f, 0.f};
#pragma unroll
    for (int dh = 0; dh < 2; dh++) {
#pragma unroll
      for (int ks = 0; ks < 4; ks++) {
        int krow = ks * 16 + l15;
        int boff = ((krow * 64 + dh * 32 + hi * 8) * 2) ^ ((krow & 7) << 4);
        short8 ak = *(const short8*)((const char*)(&Ks[buf][0]) + boff);
        sacc[ks] = __builtin_amdgcn_mfma_f32_16x16x32_bf16(ak, bq[dh], sacc[ks], 0, 0, 0);
      }
    }
    // mask + online softmax (row q = l15, spread over hi groups)
    int qg = qw + l15;
    float pv[4][4];
    float pmax = -1e30f;
#pragma unroll
    for (int ks = 0; ks < 4; ks++)
#pragma unroll
      for (int r = 0; r < 4; r++) {
        int jg = c0 + ks * 16 + hi * 4 + r;
        float s = sacc[ks][r] * 0.125f;
        bool ok = (jg <= qg) && (jg > qg - 512);
        s = ok ? s : -1e30f;
        pv[ks][r] = s;
        pmax = fmaxf(pmax, s);
      }
    pmax = fmaxf(pmax, __shfl_xor(pmax, 16));
    pmax = fmaxf(pmax, __shfl_xor(pmax, 32));
    float mnew = fmaxf(m, pmax);
    float corr = __expf(m - mnew);
    float psum = 0.f;
#pragma unroll
    for (int ks = 0; ks < 4; ks++)
#pragma unroll
      for (int r = 0; r < 4; r++) {
        float p = (pv[ks][r] > -1e29f) ? __expf(pv[ks][r] - mnew) : 0.f;
        pv[ks][r] = p;
        psum += p;
      }
    psum += __shfl_xor(psum, 16);
    psum += __shfl_xor(psum, 32);
    ssum = ssum * corr + psum;
    m = mnew;
    // rescale O rows (row q' = hi*4+r lives at lane l15==q')
#pragma unroll
    for (int r = 0; r < 4; r++) {
      float f = __shfl(corr, hi * 4 + r);
#pragma unroll
      for (int c = 0; c < 4; c++) oacc[c][r] *= f;
    }
    // P -> bf16 -> per-wave LDS (swizzled), then read as MFMA-A fragments
#pragma unroll
    for (int ks = 0; ks < 4; ks++) {
      unsigned int lo = (unsigned)bfbits(pv[ks][0]) | ((unsigned)bfbits(pv[ks][1]) << 16);
      unsigned int hi2 = (unsigned)bfbits(pv[ks][2]) | ((unsigned)bfbits(pv[ks][3]) << 16);
      int j0 = ks * 16 + hi * 4;
      int a0 = ((l15 * 64 + j0) * 2) ^ ((l15 & 7) << 4);
      int a1 = ((l15 * 64 + j0 + 2) * 2) ^ ((l15 & 7) << 4);
      *(unsigned int*)((char*)(&Ps[wid][0]) + a0) = lo;
      *(unsigned int*)((char*)(&Ps[wid][0]) + a1) = hi2;
    }
    short8 ap[2];
#pragma unroll
    for (int js = 0; js < 2; js++) {
      int a = ((l15 * 64 + js * 32 + hi * 8) * 2) ^ ((l15 & 7) << 4);
      ap[js] = *(const short8*)((const char*)(&Ps[wid][0]) + a);
    }
    // PV: A=P[16q x 32j], B=V[j][d] read from V^T LDS
#pragma unroll
    for (int js = 0; js < 2; js++)
#pragma unroll
      for (int c = 0; c < 4; c++) {
        int vrow = c * 16 + l15;
        int boff = ((vrow * 64 + js * 32 + hi * 8) * 2) ^ ((vrow & 7) << 4);
        short8 bv = *(const short8*)((const char*)(&Vs[buf][0]) + boff);
        oacc[c] = __builtin_amdgcn_mfma_f32_16x16x32_bf16(ap[js], bv, oacc[c], 0, 0, 0);
      }
    __syncthreads();
    buf ^= 1;
  }
  // epilogue: normalize, store bf16 att[b, tok, h*64+d]
  float inv = 1.f / ssum;
#pragma unroll
  for (int r = 0; r < 4; r++) {
    float f = __shfl(inv, hi * 4 + r);
    int tok = qw + hi * 4 + r;
    bf16* dst = ATT + ((size_t)b * 8192 + tok) * 1024 + h * 64;
#pragma unroll
    for (int c = 0; c < 4; c++)
      dst[c * 16 + l15] = __float2bfloat16(oacc[c][r] * f);
  }
}

extern "C" void kernel_launch(void* const* d_in, const int* in_sizes, int n_in,
                              void* d_out, int out_size, void* d_ws, size_t ws_size,
                              hipStream_t stream) {
  const float* x  = (const float*)d_in[0];
  const float* wq = (const float*)d_in[1];
  const float* wk = (const float*)d_in[2];
  const float* wv = (const float*)d_in[3];
  const float* wo = (const float*)d_in[4];
  float* out = (float*)d_out;

  char* ws = (char*)d_ws;
  const size_t SZ_X = (size_t)16384 * 1024 * 2;  // 32 MB bf16
  const size_t SZ_W = (size_t)1024 * 1024 * 2;   // 2 MB bf16
  size_t off = 0;
  bf16* xb  = (bf16*)(ws + off); off += SZ_X;
  bf16* wqb = (bf16*)(ws + off); off += SZ_W;
  bf16* wkb = (bf16*)(ws + off); off += SZ_W;
  bf16* wvb = (bf16*)(ws + off); off += SZ_W;
  bf16* wob = (bf16*)(ws + off); off += SZ_W;
  bf16* qb  = (bf16*)(ws + off); off += SZ_X;
  bf16* kb  = (bf16*)(ws + off); off += SZ_X;
  bf16* vb  = (bf16*)(ws + off); off += SZ_X;
  bf16* vtb = (bf16*)(ws + off); off += SZ_X;
  bf16* att = xb;  // alias: x_bf16 dead after QKV GEMM

  k_cvt<<<2048, 256, 0, stream>>>(x, xb, 16384 * 1024 / 8);
  k_cvt<<<512, 256, 0, stream>>>(wq, wqb, 1024 * 1024 / 8);
  k_cvt<<<512, 256, 0, stream>>>(wk, wkb, 1024 * 1024 / 8);
  k_cvt<<<512, 256, 0, stream>>>(wv, wvb, 1024 * 1024 / 8);
  k_cvt<<<512, 256, 0, stream>>>(wo, wob, 1024 * 1024 / 8);
  k_qkv_gemm<<<3072, 256, 0, stream>>>(xb, wqb, wkb, wvb, qb, kb, vb);
  k_vtrans<<<4096, 256, 0, stream>>>(vb, vtb);
  k_attn<<<4096, 256, 0, stream>>>(qb, kb, vtb, att);
  k_out_gemm<<<1024, 256, 0, stream>>>(att, wob, out);
}

// Round 3
// 332.776 us; speedup vs baseline: 1.0272x; 1.0272x over previous
//
#include <hip/hip_runtime.h>
#include <hip/hip_bf16.h>
#include <stdint.h>

typedef __attribute__((ext_vector_type(8))) short short8;
typedef __attribute__((ext_vector_type(4))) float f32x4;
typedef __hip_bfloat16 bf16;

#define AS1 __attribute__((address_space(1)))
#define AS3 __attribute__((address_space(3)))

__device__ __forceinline__ void gl16(const void* g, void* l) {
  __builtin_amdgcn_global_load_lds((const AS1 unsigned int*)g,
                                   (AS3 unsigned int*)l, 16, 0, 0);
}

__device__ __forceinline__ unsigned short bfbits(float x) {
  union { bf16 b; unsigned short u; } c; c.b = __float2bfloat16(x); return c.u;
}

#define SCHED0 __builtin_amdgcn_sched_barrier(0)

// ---------------- fp32 -> bf16 convert (vectorized) ----------------
__global__ __launch_bounds__(256) void k_cvt(const float* __restrict__ src,
                                             bf16* __restrict__ dst, int n8) {
  int i = blockIdx.x * blockDim.x + threadIdx.x;
  int stride = gridDim.x * blockDim.x;
  for (; i < n8; i += stride) {
    const float4* p = (const float4*)src + (size_t)i * 2;
    float4 a = p[0], b = p[1];
    bf16 tmp[8];
    tmp[0] = __float2bfloat16(a.x); tmp[1] = __float2bfloat16(a.y);
    tmp[2] = __float2bfloat16(a.z); tmp[3] = __float2bfloat16(a.w);
    tmp[4] = __float2bfloat16(b.x); tmp[5] = __float2bfloat16(b.y);
    tmp[6] = __float2bfloat16(b.z); tmp[7] = __float2bfloat16(b.w);
    *(short8*)(dst + (size_t)i * 8) = *(short8*)tmp;
  }
}

// ============ 256x256 GEMM, BK=32, 8 waves (2Mx4N), 4-deep counted pipeline ==
// C = A[16384,1024] * W[1024,1024]^T. LDS ring of 4 K-tile buffers (A+B),
// chunk-XOR swizzle (row&3)<<4 both-sides, vmcnt(8) counted waits (tile t+1
// landed, t+2/t+3 in flight), one s_barrier per K-tile, setprio around MFMA.
// NOTE: variadic macro — epilogue blocks contain top-level commas.

#define GEMM_BODY(...)                                                         \
  const int Kd = 1024;                                                         \
  const int nk = 32; /* 1024/32 */                                             \
  __shared__ bf16 As[4][256 * 32];                                             \
  __shared__ bf16 Bs[4][256 * 32];                                             \
  int tid = threadIdx.x;                                                       \
  int lane = tid & 63, wid = tid >> 6;                                         \
  int l15 = lane & 15, hi = lane >> 4;                                         \
  int wm = wid >> 2, wn = wid & 3;                                             \
  f32x4 acc[8][4];                                                             \
  _Pragma("unroll") for (int i = 0; i < 8; i++)                                \
      _Pragma("unroll") for (int j = 0; j < 4; j++)                            \
          acc[i][j] = (f32x4){0.f, 0.f, 0.f, 0.f};                             \
  auto stage = [&](int slot, int kk) {                                         \
    const bf16* ab = Abase + kk * 32;                                          \
    const bf16* bb = Bbase + kk * 32;                                          \
    _Pragma("unroll") for (int pass = 0; pass < 2; pass++) {                   \
      int p = pass * 512 + tid; /* [0,1024) chunks of 16B */                   \
      int row = p >> 2;                                                        \
      int u = (p & 3) ^ (row & 3); /* inverse-swizzled source */               \
      gl16(ab + (size_t)row * Kd + u * 8, (char*)(&As[slot][0]) + p * 16);     \
      gl16(bb + (size_t)row * Kd + u * 8, (char*)(&Bs[slot][0]) + p * 16);     \
    }                                                                          \
  };                                                                           \
  stage(0, 0); stage(1, 1); stage(2, 2);                                       \
  asm volatile("s_waitcnt vmcnt(8)" ::: "memory");                             \
  SCHED0; __builtin_amdgcn_s_barrier(); SCHED0;                                \
  int sw = (l15 & 3) << 4;                                                     \
  for (int t = 0; t < nk; ++t) {                                               \
    int slot = t & 3;                                                          \
    const char* Ab = (const char*)(&As[slot][0]);                              \
    const char* Bb = (const char*)(&Bs[slot][0]);                              \
    if (t + 3 < nk) stage((t + 3) & 3, t + 3);                                 \
    short8 afr[8], bfr[4];                                                     \
    _Pragma("unroll") for (int mf = 0; mf < 8; mf++) {                         \
      int row = wm * 128 + mf * 16 + l15;                                      \
      afr[mf] = *(const short8*)(Ab + ((row * 64 + hi * 16) ^ sw));            \
    }                                                                          \
    _Pragma("unroll") for (int nf = 0; nf < 4; nf++) {                         \
      int row = wn * 64 + nf * 16 + l15;                                       \
      bfr[nf] = *(const short8*)(Bb + ((row * 64 + hi * 16) ^ sw));            \
    }                                                                          \
    __builtin_amdgcn_s_setprio(1);                                             \
    _Pragma("unroll") for (int mf = 0; mf < 8; mf++)                           \
        _Pragma("unroll") for (int nf = 0; nf < 4; nf++)                       \
            acc[mf][nf] = __builtin_amdgcn_mfma_f32_16x16x32_bf16(             \
                afr[mf], bfr[nf], acc[mf][nf], 0, 0, 0);                       \
    __builtin_amdgcn_s_setprio(0);                                             \
    if (t + 1 < nk) {                                                          \
      SCHED0;                                                                  \
      if (t + 3 < nk)      asm volatile("s_waitcnt vmcnt(8)" ::: "memory");    \
      else if (t + 2 < nk) asm volatile("s_waitcnt vmcnt(4)" ::: "memory");    \
      else                 asm volatile("s_waitcnt vmcnt(0)" ::: "memory");    \
      SCHED0; __builtin_amdgcn_s_barrier(); SCHED0;                            \
    }                                                                          \
  }                                                                            \
  __VA_ARGS__

__global__ __launch_bounds__(512, 2) void k_qkv_gemm(
    const bf16* __restrict__ X, const bf16* __restrict__ Wq,
    const bf16* __restrict__ Wk, const bf16* __restrict__ Wv,
    bf16* __restrict__ Q, bf16* __restrict__ K, bf16* __restrict__ V) {
  int bid = blockIdx.x;
  int wsel = bid >> 8;       // 0..2 : q,k,v
  int rem = bid & 255;
  int mt = rem & 63;
  int nt = rem >> 6;
  const bf16* W = (wsel == 0) ? Wq : (wsel == 1) ? Wk : Wv;
  bf16* Dst = (wsel == 0) ? Q : (wsel == 1) ? K : V;
  const bf16* Abase = X + (size_t)mt * 256 * 1024;
  const bf16* Bbase = W + (size_t)nt * 256 * 1024;
  GEMM_BODY({
    _Pragma("unroll") for (int mf = 0; mf < 8; mf++) {
      _Pragma("unroll") for (int r = 0; r < 4; r++) {
        int row = mt * 256 + wm * 128 + mf * 16 + hi * 4 + r;  // token
        int b = row >> 13;
        int tok = row & 8191;
        _Pragma("unroll") for (int nf = 0; nf < 4; nf++) {
          int col = nt * 256 + wn * 64 + nf * 16 + l15;        // channel
          int h = col >> 6;
          int d = col & 63;
          Dst[((size_t)(b * 16 + h) * 8192 + tok) * 64 + d] =
              __float2bfloat16(acc[mf][nf][r]);
        }
      }
    }
  })
}

__global__ __launch_bounds__(512, 2) void k_out_gemm(
    const bf16* __restrict__ A, const bf16* __restrict__ Wo,
    float* __restrict__ Out) {
  int bid = blockIdx.x;
  int mt = bid & 63;
  int nt = bid >> 6;
  const bf16* Abase = A + (size_t)mt * 256 * 1024;
  const bf16* Bbase = Wo + (size_t)nt * 256 * 1024;
  GEMM_BODY({
    _Pragma("unroll") for (int mf = 0; mf < 8; mf++) {
      _Pragma("unroll") for (int r = 0; r < 4; r++) {
        int row = mt * 256 + wm * 128 + mf * 16 + hi * 4 + r;
        _Pragma("unroll") for (int nf = 0; nf < 4; nf++) {
          int col = nt * 256 + wn * 64 + nf * 16 + l15;
          Out[(size_t)row * 1024 + col] = acc[mf][nf][r];
        }
      }
    }
  })
}

// ---------------- V transpose: [B,H,T,D] -> [B,H,D,T] ----------------
__global__ __launch_bounds__(256) void k_vtrans(const bf16* __restrict__ V,
                                                bf16* __restrict__ VT) {
  const int T = 8192;
  __shared__ bf16 tile[64][72];
  int bid = blockIdx.x;
  int tb = bid & 127;
  int bh = bid >> 7;
  int t0 = tb * 64;
  int tid = threadIdx.x;
  int r = tid >> 2, c4 = tid & 3;
  const bf16* src = V + ((size_t)bh * T + t0 + r) * 64 + c4 * 16;
  short8 a = *(const short8*)src;
  short8 b2 = *(const short8*)(src + 8);
#pragma unroll
  for (int e = 0; e < 8; e++) tile[r][c4 * 16 + e] = ((bf16*)&a)[e];
#pragma unroll
  for (int e = 0; e < 8; e++) tile[r][c4 * 16 + 8 + e] = ((bf16*)&b2)[e];
  __syncthreads();
  alignas(16) bf16 o[16];
#pragma unroll
  for (int e = 0; e < 16; e++) o[e] = tile[c4 * 16 + e][r];
  bf16* dst = VT + ((size_t)bh * 64 + r) * T + t0 + c4 * 16;
  *(short8*)dst = *(short8*)o;
  *(short8*)(dst + 8) = *((short8*)o + 1);
}

// ---------------- sliding-window attention ----------------
__global__ __launch_bounds__(256) void k_attn(
    const bf16* __restrict__ Q, const bf16* __restrict__ K,
    const bf16* __restrict__ VT, bf16* __restrict__ ATT) {
  const int T = 8192;
  __shared__ bf16 Ks[2][64 * 64];
  __shared__ bf16 Vs[2][64 * 64];  // V^T chunk: [d][j]
  __shared__ bf16 Ps[4][16 * 64];  // per-wave P
  int bid = blockIdx.x;
  int qt = bid & 127;
  int bh = bid >> 7;  // 0..31
  int b = bh >> 4, h = bh & 15;
  int tid = threadIdx.x;
  int lane = tid & 63, wid = tid >> 6;
  int l15 = lane & 15, hi = lane >> 4;
  int q0 = qt * 64;
  int qw = q0 + wid * 16;

  short8 bq[2];
  const bf16* qp = Q + ((size_t)bh * T + qw + l15) * 64 + hi * 8;
  bq[0] = *(const short8*)qp;
  bq[1] = *(const short8*)(qp + 32);

  const bf16* Kbh = K + (size_t)bh * T * 64;
  const bf16* Vbh = VT + (size_t)bh * 64 * T;

  auto stage = [&](int bb, int c0) {
#pragma unroll
    for (int pass = 0; pass < 2; pass++) {
      int p = pass * 256 + tid;
      int row = p >> 3;
      int u = (p & 7) ^ (row & 7);
      gl16(Kbh + ((size_t)(c0 + row)) * 64 + u * 8, (char*)(&Ks[bb][0]) + p * 16);
      gl16(Vbh + (size_t)row * T + c0 + u * 8, (char*)(&Vs[bb][0]) + p * 16);
    }
  };

  int cstart = q0 - 512; if (cstart < 0) cstart = 0;
  int nch = (q0 + 64 - cstart) >> 6;

  f32x4 oacc[4];
#pragma unroll
  for (int c = 0; c < 4; c++) oacc[c] = (f32x4){0.f, 0.f, 0.f, 0.f};
  float m = -1e30f, ssum = 0.f;

  stage(0, cstart);
  __syncthreads();
  int buf = 0;
  for (int ci = 0; ci < nch; ci++) {
    int c0 = cstart + (ci << 6);
    if (ci + 1 < nch) stage(buf ^ 1, c0 + 64);
    f32x4 sacc[4];
#pragma unroll
    for (int ks = 0; ks < 4; ks++) sacc[ks] = (f32x4){0.f, 0.f, 0.f, 0.f};
#pragma unroll
    for (int dh = 0; dh < 2; dh++) {
#pragma unroll
      for (int ks = 0; ks < 4; ks++) {
        int krow = ks * 16 + l15;
        int boff = ((krow * 64 + dh * 32 + hi * 8) * 2) ^ ((krow & 7) << 4);
        short8 ak = *(const short8*)((const char*)(&Ks[buf][0]) + boff);
        sacc[ks] = __builtin_amdgcn_mfma_f32_16x16x32_bf16(ak, bq[dh], sacc[ks], 0, 0, 0);
      }
    }
    int qg = qw + l15;
    float pv[4][4];
    float pmax = -1e30f;
#pragma unroll
    for (int ks = 0; ks < 4; ks++)
#pragma unroll
      for (int r = 0; r < 4; r++) {
        int jg = c0 + ks * 16 + hi * 4 + r;
        float s = sacc[ks][r] * 0.125f;
        bool ok = (jg <= qg) && (jg > qg - 512);
        s = ok ? s : -1e30f;
        pv[ks][r] = s;
        pmax = fmaxf(pmax, s);
      }
    pmax = fmaxf(pmax, __shfl_xor(pmax, 16));
    pmax = fmaxf(pmax, __shfl_xor(pmax, 32));
    float mnew = fmaxf(m, pmax);
    float corr = __expf(m - mnew);
    float psum = 0.f;
#pragma unroll
    for (int ks = 0; ks < 4; ks++)
#pragma unroll
      for (int r = 0; r < 4; r++) {
        float p = (pv[ks][r] > -1e29f) ? __expf(pv[ks][r] - mnew) : 0.f;
        pv[ks][r] = p;
        psum += p;
      }
    psum += __shfl_xor(psum, 16);
    psum += __shfl_xor(psum, 32);
    ssum = ssum * corr + psum;
    m = mnew;
#pragma unroll
    for (int r = 0; r < 4; r++) {
      float f = __shfl(corr, hi * 4 + r);
#pragma unroll
      for (int c = 0; c < 4; c++) oacc[c][r] *= f;
    }
#pragma unroll
    for (int ks = 0; ks < 4; ks++) {
      unsigned int lo = (unsigned)bfbits(pv[ks][0]) | ((unsigned)bfbits(pv[ks][1]) << 16);
      unsigned int hi2 = (unsigned)bfbits(pv[ks][2]) | ((unsigned)bfbits(pv[ks][3]) << 16);
      int j0 = ks * 16 + hi * 4;
      int a0 = ((l15 * 64 + j0) * 2) ^ ((l15 & 7) << 4);
      int a1 = ((l15 * 64 + j0 + 2) * 2) ^ ((l15 & 7) << 4);
      *(unsigned int*)((char*)(&Ps[wid][0]) + a0) = lo;
      *(unsigned int*)((char*)(&Ps[wid][0]) + a1) = hi2;
    }
    short8 ap[2];
#pragma unroll
    for (int js = 0; js < 2; js++) {
      int a = ((l15 * 64 + js * 32 + hi * 8) * 2) ^ ((l15 & 7) << 4);
      ap[js] = *(const short8*)((const char*)(&Ps[wid][0]) + a);
    }
#pragma unroll
    for (int js = 0; js < 2; js++)
#pragma unroll
      for (int c = 0; c < 4; c++) {
        int vrow = c * 16 + l15;
        int boff = ((vrow * 64 + js * 32 + hi * 8) * 2) ^ ((vrow & 7) << 4);
        short8 bv = *(const short8*)((const char*)(&Vs[buf][0]) + boff);
        oacc[c] = __builtin_amdgcn_mfma_f32_16x16x32_bf16(ap[js], bv, oacc[c], 0, 0, 0);
      }
    __syncthreads();
    buf ^= 1;
  }
  float inv = 1.f / ssum;
#pragma unroll
  for (int r = 0; r < 4; r++) {
    float f = __shfl(inv, hi * 4 + r);
    int tok = qw + hi * 4 + r;
    bf16* dst = ATT + ((size_t)b * 8192 + tok) * 1024 + h * 64;
#pragma unroll
    for (int c = 0; c < 4; c++)
      dst[c * 16 + l15] = __float2bfloat16(oacc[c][r] * f);
  }
}

extern "C" void kernel_launch(void* const* d_in, const int* in_sizes, int n_in,
                              void* d_out, int out_size, void* d_ws, size_t ws_size,
                              hipStream_t stream) {
  const float* x  = (const float*)d_in[0];
  const float* wq = (const float*)d_in[1];
  const float* wk = (const float*)d_in[2];
  const float* wv = (const float*)d_in[3];
  const float* wo = (const float*)d_in[4];
  float* out = (float*)d_out;

  char* ws = (char*)d_ws;
  const size_t SZ_X = (size_t)16384 * 1024 * 2;  // 32 MB bf16
  const size_t SZ_W = (size_t)1024 * 1024 * 2;   // 2 MB bf16
  size_t off = 0;
  bf16* xb  = (bf16*)(ws + off); off += SZ_X;
  bf16* wqb = (bf16*)(ws + off); off += SZ_W;
  bf16* wkb = (bf16*)(ws + off); off += SZ_W;
  bf16* wvb = (bf16*)(ws + off); off += SZ_W;
  bf16* wob = (bf16*)(ws + off); off += SZ_W;
  bf16* qb  = (bf16*)(ws + off); off += SZ_X;
  bf16* kb  = (bf16*)(ws + off); off += SZ_X;
  bf16* vb  = (bf16*)(ws + off); off += SZ_X;
  bf16* vtb = (bf16*)(ws + off); off += SZ_X;
  bf16* att = xb;  // alias: x_bf16 dead after QKV GEMM

  k_cvt<<<2048, 256, 0, stream>>>(x, xb, 16384 * 1024 / 8);
  k_cvt<<<512, 256, 0, stream>>>(wq, wqb, 1024 * 1024 / 8);
  k_cvt<<<512, 256, 0, stream>>>(wk, wkb, 1024 * 1024 / 8);
  k_cvt<<<512, 256, 0, stream>>>(wv, wvb, 1024 * 1024 / 8);
  k_cvt<<<512, 256, 0, stream>>>(wo, wob, 1024 * 1024 / 8);
  k_qkv_gemm<<<768, 512, 0, stream>>>(xb, wqb, wkb, wvb, qb, kb, vb);
  k_vtrans<<<4096, 256, 0, stream>>>(vb, vtb);
  k_attn<<<4096, 256, 0, stream>>>(qb, kb, vtb, att);
  k_out_gemm<<<256, 512, 0, stream>>>(att, wob, out);
}

// Round 4
// 327.485 us; speedup vs baseline: 1.0438x; 1.0162x over previous
//
#include <hip/hip_runtime.h>
#include <hip/hip_bf16.h>
#include <stdint.h>

typedef __attribute__((ext_vector_type(8))) short short8;
typedef __attribute__((ext_vector_type(4))) float f32x4;
typedef __hip_bfloat16 bf16;

#define AS1 __attribute__((address_space(1)))
#define AS3 __attribute__((address_space(3)))

__device__ __forceinline__ void gl16(const void* g, void* l) {
  __builtin_amdgcn_global_load_lds((const AS1 unsigned int*)g,
                                   (AS3 unsigned int*)l, 16, 0, 0);
}

__device__ __forceinline__ unsigned short bfbits(float x) {
  union { bf16 b; unsigned short u; } c; c.b = __float2bfloat16(x); return c.u;
}

#define SCHED0 __builtin_amdgcn_sched_barrier(0)

// ---------------- fp32 -> bf16 convert (vectorized) ----------------
__global__ __launch_bounds__(256) void k_cvt(const float* __restrict__ src,
                                             bf16* __restrict__ dst, int n8) {
  int i = blockIdx.x * blockDim.x + threadIdx.x;
  int stride = gridDim.x * blockDim.x;
  for (; i < n8; i += stride) {
    const float4* p = (const float4*)src + (size_t)i * 2;
    float4 a = p[0], b = p[1];
    bf16 tmp[8];
    tmp[0] = __float2bfloat16(a.x); tmp[1] = __float2bfloat16(a.y);
    tmp[2] = __float2bfloat16(a.z); tmp[3] = __float2bfloat16(a.w);
    tmp[4] = __float2bfloat16(b.x); tmp[5] = __float2bfloat16(b.y);
    tmp[6] = __float2bfloat16(b.z); tmp[7] = __float2bfloat16(b.w);
    *(short8*)(dst + (size_t)i * 8) = *(short8*)tmp;
  }
}

// ============ 256x256 GEMM, BK=32, 8 waves (2Mx4N), 4-deep ring ============
// 2 phases per K-tile (16 MFMA each), per-phase {ds_read || stage -> barrier
// -> setprio MFMA -> barrier}, counted vmcnt(8) once per tile (never 0 in
// steady state). Chunk-XOR swizzle ((row>>1)&3)<<4 both-sides: per quarter-
// wave every 16B bank-group hit exactly 2x (free), 8x per wave (minimum).

#define GEMM_BODY(...)                                                         \
  const int Kd = 1024;                                                         \
  const int nk = 32; /* 1024/32 */                                             \
  __shared__ bf16 As[4][256 * 32];                                             \
  __shared__ bf16 Bs[4][256 * 32];                                             \
  int tid = threadIdx.x;                                                       \
  int lane = tid & 63, wid = tid >> 6;                                         \
  int l15 = lane & 15, hi = lane >> 4;                                         \
  int wm = wid >> 2, wn = wid & 3;                                             \
  f32x4 acc[8][4];                                                             \
  _Pragma("unroll") for (int i = 0; i < 8; i++)                                \
      _Pragma("unroll") for (int j = 0; j < 4; j++)                            \
          acc[i][j] = (f32x4){0.f, 0.f, 0.f, 0.f};                             \
  auto stageA = [&](int slot, int kk) {                                        \
    const bf16* ab = Abase + kk * 32;                                          \
    _Pragma("unroll") for (int pass = 0; pass < 2; pass++) {                   \
      int p = pass * 512 + tid;                                                \
      int row = p >> 2;                                                        \
      int u = (p & 3) ^ ((row >> 1) & 3);                                      \
      gl16(ab + (size_t)row * Kd + u * 8, (char*)(&As[slot][0]) + p * 16);     \
    }                                                                          \
  };                                                                           \
  auto stageB = [&](int slot, int kk) {                                        \
    const bf16* bb = Bbase + kk * 32;                                          \
    _Pragma("unroll") for (int pass = 0; pass < 2; pass++) {                   \
      int p = pass * 512 + tid;                                                \
      int row = p >> 2;                                                        \
      int u = (p & 3) ^ ((row >> 1) & 3);                                      \
      gl16(bb + (size_t)row * Kd + u * 8, (char*)(&Bs[slot][0]) + p * 16);     \
    }                                                                          \
  };                                                                           \
  stageA(0, 0); stageB(0, 0);                                                  \
  stageA(1, 1); stageB(1, 1);                                                  \
  stageA(2, 2); stageB(2, 2);                                                  \
  asm volatile("s_waitcnt vmcnt(8)" ::: "memory");                             \
  SCHED0; __builtin_amdgcn_s_barrier(); SCHED0;                                \
  int sw = ((l15 >> 1) & 3) << 4;                                              \
  for (int t = 0; t < nk; ++t) {                                               \
    int slot = t & 3;                                                          \
    const char* Ab = (const char*)(&As[slot][0]);                              \
    const char* Bb = (const char*)(&Bs[slot][0]);                              \
    /* ---- PHASE A: stage A(t+3) || read A0-3,B0-3 -> 16 MFMA ---- */         \
    if (t + 3 < nk) stageA((t + 3) & 3, t + 3);                                \
    short8 afr[4], bfr[4];                                                     \
    _Pragma("unroll") for (int mf = 0; mf < 4; mf++) {                         \
      int row = wm * 128 + mf * 16 + l15;                                      \
      afr[mf] = *(const short8*)(Ab + ((row * 64 + hi * 16) ^ sw));            \
    }                                                                          \
    _Pragma("unroll") for (int nf = 0; nf < 4; nf++) {                         \
      int row = wn * 64 + nf * 16 + l15;                                       \
      bfr[nf] = *(const short8*)(Bb + ((row * 64 + hi * 16) ^ sw));            \
    }                                                                          \
    SCHED0; __builtin_amdgcn_s_barrier(); SCHED0;                              \
    __builtin_amdgcn_s_setprio(1);                                             \
    _Pragma("unroll") for (int mf = 0; mf < 4; mf++)                           \
        _Pragma("unroll") for (int nf = 0; nf < 4; nf++)                       \
            acc[mf][nf] = __builtin_amdgcn_mfma_f32_16x16x32_bf16(             \
                afr[mf], bfr[nf], acc[mf][nf], 0, 0, 0);                       \
    __builtin_amdgcn_s_setprio(0);                                             \
    SCHED0; __builtin_amdgcn_s_barrier(); SCHED0;                              \
    /* ---- PHASE B: stage B(t+3) || read A4-7 -> 16 MFMA ---- */              \
    if (t + 3 < nk) stageB((t + 3) & 3, t + 3);                                \
    short8 afr2[4];                                                            \
    _Pragma("unroll") for (int mf = 0; mf < 4; mf++) {                         \
      int row = wm * 128 + 64 + mf * 16 + l15;                                 \
      afr2[mf] = *(const short8*)(Ab + ((row * 64 + hi * 16) ^ sw));           \
    }                                                                          \
    SCHED0;                                                                    \
    if (t + 3 < nk)      asm volatile("s_waitcnt vmcnt(8)" ::: "memory");      \
    else if (t + 2 < nk) asm volatile("s_waitcnt vmcnt(4)" ::: "memory");      \
    else if (t + 1 < nk) asm volatile("s_waitcnt vmcnt(0)" ::: "memory");      \
    SCHED0; __builtin_amdgcn_s_barrier(); SCHED0;                              \
    __builtin_amdgcn_s_setprio(1);                                             \
    _Pragma("unroll") for (int mf = 0; mf < 4; mf++)                           \
        _Pragma("unroll") for (int nf = 0; nf < 4; nf++)                       \
            acc[mf + 4][nf] = __builtin_amdgcn_mfma_f32_16x16x32_bf16(         \
                afr2[mf], bfr[nf], acc[mf + 4][nf], 0, 0, 0);                  \
    __builtin_amdgcn_s_setprio(0);                                             \
    if (t + 1 < nk) { SCHED0; __builtin_amdgcn_s_barrier(); SCHED0; }          \
  }                                                                            \
  __VA_ARGS__

__global__ __launch_bounds__(512, 2) void k_qkv_gemm(
    const bf16* __restrict__ X, const bf16* __restrict__ Wq,
    const bf16* __restrict__ Wk, const bf16* __restrict__ Wv,
    bf16* __restrict__ Q, bf16* __restrict__ K, bf16* __restrict__ V) {
  int bid = blockIdx.x;
  int wsel = bid >> 8;       // 0..2 : q,k,v
  int rem = bid & 255;
  int mt = rem & 63;
  int nt = rem >> 6;
  const bf16* W = (wsel == 0) ? Wq : (wsel == 1) ? Wk : Wv;
  bf16* Dst = (wsel == 0) ? Q : (wsel == 1) ? K : V;
  const bf16* Abase = X + (size_t)mt * 256 * 1024;
  const bf16* Bbase = W + (size_t)nt * 256 * 1024;
  GEMM_BODY({
    _Pragma("unroll") for (int mf = 0; mf < 8; mf++) {
      _Pragma("unroll") for (int r = 0; r < 4; r++) {
        int row = mt * 256 + wm * 128 + mf * 16 + hi * 4 + r;  // token
        int b = row >> 13;
        int tok = row & 8191;
        _Pragma("unroll") for (int nf = 0; nf < 4; nf++) {
          int col = nt * 256 + wn * 64 + nf * 16 + l15;        // channel
          int h = col >> 6;
          int d = col & 63;
          Dst[((size_t)(b * 16 + h) * 8192 + tok) * 64 + d] =
              __float2bfloat16(acc[mf][nf][r]);
        }
      }
    }
  })
}

__global__ __launch_bounds__(512, 2) void k_out_gemm(
    const bf16* __restrict__ A, const bf16* __restrict__ Wo,
    float* __restrict__ Out) {
  int bid = blockIdx.x;
  int mt = bid & 63;
  int nt = bid >> 6;
  const bf16* Abase = A + (size_t)mt * 256 * 1024;
  const bf16* Bbase = Wo + (size_t)nt * 256 * 1024;
  GEMM_BODY({
    _Pragma("unroll") for (int mf = 0; mf < 8; mf++) {
      _Pragma("unroll") for (int r = 0; r < 4; r++) {
        int row = mt * 256 + wm * 128 + mf * 16 + hi * 4 + r;
        _Pragma("unroll") for (int nf = 0; nf < 4; nf++) {
          int col = nt * 256 + wn * 64 + nf * 16 + l15;
          Out[(size_t)row * 1024 + col] = acc[mf][nf][r];
        }
      }
    }
  })
}

// ---------------- V transpose: [B,H,T,D] -> [B,H,D,T] ----------------
__global__ __launch_bounds__(256) void k_vtrans(const bf16* __restrict__ V,
                                                bf16* __restrict__ VT) {
  const int T = 8192;
  __shared__ bf16 tile[64][72];
  int bid = blockIdx.x;
  int tb = bid & 127;
  int bh = bid >> 7;
  int t0 = tb * 64;
  int tid = threadIdx.x;
  int r = tid >> 2, c4 = tid & 3;
  const bf16* src = V + ((size_t)bh * T + t0 + r) * 64 + c4 * 16;
  short8 a = *(const short8*)src;
  short8 b2 = *(const short8*)(src + 8);
#pragma unroll
  for (int e = 0; e < 8; e++) tile[r][c4 * 16 + e] = ((bf16*)&a)[e];
#pragma unroll
  for (int e = 0; e < 8; e++) tile[r][c4 * 16 + 8 + e] = ((bf16*)&b2)[e];
  __syncthreads();
  alignas(16) bf16 o[16];
#pragma unroll
  for (int e = 0; e < 16; e++) o[e] = tile[c4 * 16 + e][r];
  bf16* dst = VT + ((size_t)bh * 64 + r) * T + t0 + c4 * 16;
  *(short8*)dst = *(short8*)o;
  *(short8*)(dst + 8) = *((short8*)o + 1);
}

// ---------------- sliding-window attention ----------------
__global__ __launch_bounds__(256) void k_attn(
    const bf16* __restrict__ Q, const bf16* __restrict__ K,
    const bf16* __restrict__ VT, bf16* __restrict__ ATT) {
  const int T = 8192;
  __shared__ bf16 Ks[2][64 * 64];
  __shared__ bf16 Vs[2][64 * 64];  // V^T chunk: [d][j]
  __shared__ bf16 Ps[4][16 * 64];  // per-wave P
  int bid = blockIdx.x;
  int qt = bid & 127;
  int bh = bid >> 7;  // 0..31
  int b = bh >> 4, h = bh & 15;
  int tid = threadIdx.x;
  int lane = tid & 63, wid = tid >> 6;
  int l15 = lane & 15, hi = lane >> 4;
  int q0 = qt * 64;
  int qw = q0 + wid * 16;

  short8 bq[2];
  const bf16* qp = Q + ((size_t)bh * T + qw + l15) * 64 + hi * 8;
  bq[0] = *(const short8*)qp;
  bq[1] = *(const short8*)(qp + 32);

  const bf16* Kbh = K + (size_t)bh * T * 64;
  const bf16* Vbh = VT + (size_t)bh * 64 * T;

  auto stage = [&](int bb, int c0) {
#pragma unroll
    for (int pass = 0; pass < 2; pass++) {
      int p = pass * 256 + tid;
      int row = p >> 3;
      int u = (p & 7) ^ (row & 7);
      gl16(Kbh + ((size_t)(c0 + row)) * 64 + u * 8, (char*)(&Ks[bb][0]) + p * 16);
      gl16(Vbh + (size_t)row * T + c0 + u * 8, (char*)(&Vs[bb][0]) + p * 16);
    }
  };

  int cstart = q0 - 512; if (cstart < 0) cstart = 0;
  int nch = (q0 + 64 - cstart) >> 6;

  f32x4 oacc[4];
#pragma unroll
  for (int c = 0; c < 4; c++) oacc[c] = (f32x4){0.f, 0.f, 0.f, 0.f};
  float m = -1e30f, ssum = 0.f;

  stage(0, cstart);
  __syncthreads();
  int buf = 0;
  for (int ci = 0; ci < nch; ci++) {
    int c0 = cstart + (ci << 6);
    if (ci + 1 < nch) stage(buf ^ 1, c0 + 64);
    f32x4 sacc[4];
#pragma unroll
    for (int ks = 0; ks < 4; ks++) sacc[ks] = (f32x4){0.f, 0.f, 0.f, 0.f};
#pragma unroll
    for (int dh = 0; dh < 2; dh++) {
#pragma unroll
      for (int ks = 0; ks < 4; ks++) {
        int krow = ks * 16 + l15;
        int boff = ((krow * 64 + dh * 32 + hi * 8) * 2) ^ ((krow & 7) << 4);
        short8 ak = *(const short8*)((const char*)(&Ks[buf][0]) + boff);
        sacc[ks] = __builtin_amdgcn_mfma_f32_16x16x32_bf16(ak, bq[dh], sacc[ks], 0, 0, 0);
      }
    }
    int qg = qw + l15;
    float pv[4][4];
    float pmax = -1e30f;
#pragma unroll
    for (int ks = 0; ks < 4; ks++)
#pragma unroll
      for (int r = 0; r < 4; r++) {
        int jg = c0 + ks * 16 + hi * 4 + r;
        float s = sacc[ks][r] * 0.125f;
        bool ok = (jg <= qg) && (jg > qg - 512);
        s = ok ? s : -1e30f;
        pv[ks][r] = s;
        pmax = fmaxf(pmax, s);
      }
    pmax = fmaxf(pmax, __shfl_xor(pmax, 16));
    pmax = fmaxf(pmax, __shfl_xor(pmax, 32));
    float mnew = fmaxf(m, pmax);
    float corr = __expf(m - mnew);
    float psum = 0.f;
#pragma unroll
    for (int ks = 0; ks < 4; ks++)
#pragma unroll
      for (int r = 0; r < 4; r++) {
        float p = (pv[ks][r] > -1e29f) ? __expf(pv[ks][r] - mnew) : 0.f;
        pv[ks][r] = p;
        psum += p;
      }
    psum += __shfl_xor(psum, 16);
    psum += __shfl_xor(psum, 32);
    ssum = ssum * corr + psum;
    m = mnew;
#pragma unroll
    for (int r = 0; r < 4; r++) {
      float f = __shfl(corr, hi * 4 + r);
#pragma unroll
      for (int c = 0; c < 4; c++) oacc[c][r] *= f;
    }
#pragma unroll
    for (int ks = 0; ks < 4; ks++) {
      unsigned int lo = (unsigned)bfbits(pv[ks][0]) | ((unsigned)bfbits(pv[ks][1]) << 16);
      unsigned int hi2 = (unsigned)bfbits(pv[ks][2]) | ((unsigned)bfbits(pv[ks][3]) << 16);
      int j0 = ks * 16 + hi * 4;
      int a0 = ((l15 * 64 + j0) * 2) ^ ((l15 & 7) << 4);
      int a1 = ((l15 * 64 + j0 + 2) * 2) ^ ((l15 & 7) << 4);
      *(unsigned int*)((char*)(&Ps[wid][0]) + a0) = lo;
      *(unsigned int*)((char*)(&Ps[wid][0]) + a1) = hi2;
    }
    short8 ap[2];
#pragma unroll
    for (int js = 0; js < 2; js++) {
      int a = ((l15 * 64 + js * 32 + hi * 8) * 2) ^ ((l15 & 7) << 4);
      ap[js] = *(const short8*)((const char*)(&Ps[wid][0]) + a);
    }
#pragma unroll
    for (int js = 0; js < 2; js++)
#pragma unroll
      for (int c = 0; c < 4; c++) {
        int vrow = c * 16 + l15;
        int boff = ((vrow * 64 + js * 32 + hi * 8) * 2) ^ ((vrow & 7) << 4);
        short8 bv = *(const short8*)((const char*)(&Vs[buf][0]) + boff);
        oacc[c] = __builtin_amdgcn_mfma_f32_16x16x32_bf16(ap[js], bv, oacc[c], 0, 0, 0);
      }
    __syncthreads();
    buf ^= 1;
  }
  float inv = 1.f / ssum;
#pragma unroll
  for (int r = 0; r < 4; r++) {
    float f = __shfl(inv, hi * 4 + r);
    int tok = qw + hi * 4 + r;
    bf16* dst = ATT + ((size_t)b * 8192 + tok) * 1024 + h * 64;
#pragma unroll
    for (int c = 0; c < 4; c++)
      dst[c * 16 + l15] = __float2bfloat16(oacc[c][r] * f);
  }
}

extern "C" void kernel_launch(void* const* d_in, const int* in_sizes, int n_in,
                              void* d_out, int out_size, void* d_ws, size_t ws_size,
                              hipStream_t stream) {
  const float* x  = (const float*)d_in[0];
  const float* wq = (const float*)d_in[1];
  const float* wk = (const float*)d_in[2];
  const float* wv = (const float*)d_in[3];
  const float* wo = (const float*)d_in[4];
  float* out = (float*)d_out;

  char* ws = (char*)d_ws;
  const size_t SZ_X = (size_t)16384 * 1024 * 2;  // 32 MB bf16
  const size_t SZ_W = (size_t)1024 * 1024 * 2;   // 2 MB bf16
  size_t off = 0;
  bf16* xb  = (bf16*)(ws + off); off += SZ_X;
  bf16* wqb = (bf16*)(ws + off); off += SZ_W;
  bf16* wkb = (bf16*)(ws + off); off += SZ_W;
  bf16* wvb = (bf16*)(ws + off); off += SZ_W;
  bf16* wob = (bf16*)(ws + off); off += SZ_W;
  bf16* qb  = (bf16*)(ws + off); off += SZ_X;
  bf16* kb  = (bf16*)(ws + off); off += SZ_X;
  bf16* vb  = (bf16*)(ws + off); off += SZ_X;
  bf16* vtb = (bf16*)(ws + off); off += SZ_X;
  bf16* att = xb;  // alias: x_bf16 dead after QKV GEMM

  k_cvt<<<2048, 256, 0, stream>>>(x, xb, 16384 * 1024 / 8);
  k_cvt<<<512, 256, 0, stream>>>(wq, wqb, 1024 * 1024 / 8);
  k_cvt<<<512, 256, 0, stream>>>(wk, wkb, 1024 * 1024 / 8);
  k_cvt<<<512, 256, 0, stream>>>(wv, wvb, 1024 * 1024 / 8);
  k_cvt<<<512, 256, 0, stream>>>(wo, wob, 1024 * 1024 / 8);
  k_qkv_gemm<<<768, 512, 0, stream>>>(xb, wqb, wkb, wvb, qb, kb, vb);
  k_vtrans<<<4096, 256, 0, stream>>>(vb, vtb);
  k_attn<<<4096, 256, 0, stream>>>(qb, kb, vtb, att);
  k_out_gemm<<<256, 512, 0, stream>>>(att, wob, out);
}

// Round 5
// 310.404 us; speedup vs baseline: 1.1012x; 1.0550x over previous
//
#include <hip/hip_runtime.h>
#include <hip/hip_bf16.h>
#include <stdint.h>

typedef __attribute__((ext_vector_type(8))) short short8;
typedef __attribute__((ext_vector_type(4))) float f32x4;
typedef __hip_bfloat16 bf16;

#define AS1 __attribute__((address_space(1)))
#define AS3 __attribute__((address_space(3)))

__device__ __forceinline__ void gl16(const void* g, void* l) {
  __builtin_amdgcn_global_load_lds((const AS1 unsigned int*)g,
                                   (AS3 unsigned int*)l, 16, 0, 0);
}

__device__ __forceinline__ unsigned short bfbits(float x) {
  union { bf16 b; unsigned short u; } c; c.b = __float2bfloat16(x); return c.u;
}

#define SCHED0 __builtin_amdgcn_sched_barrier(0)

// ---------------- fp32 -> bf16 convert (vectorized) ----------------
__global__ __launch_bounds__(256) void k_cvt(const float* __restrict__ src,
                                             bf16* __restrict__ dst, int n8) {
  int i = blockIdx.x * blockDim.x + threadIdx.x;
  int stride = gridDim.x * blockDim.x;
  for (; i < n8; i += stride) {
    const float4* p = (const float4*)src + (size_t)i * 2;
    float4 a = p[0], b = p[1];
    bf16 tmp[8];
    tmp[0] = __float2bfloat16(a.x); tmp[1] = __float2bfloat16(a.y);
    tmp[2] = __float2bfloat16(a.z); tmp[3] = __float2bfloat16(a.w);
    tmp[4] = __float2bfloat16(b.x); tmp[5] = __float2bfloat16(b.y);
    tmp[6] = __float2bfloat16(b.z); tmp[7] = __float2bfloat16(b.w);
    *(short8*)(dst + (size_t)i * 8) = *(short8*)tmp;
  }
}

// ============ 256x256 GEMM, BK=32, 8 waves (2Mx4N), 4-slot ring ============
// Register-pipelined phases: each phase issues the NEXT phase's ds_reads
// before its own MFMA cluster, so the LDS drain overlaps the MFMA (compiler
// emits counted lgkmcnt gating only the previous phase's reads). Counted
// vmcnt(8) once per tile; 2 barriers per tile; zero-conflict chunk swizzle.

#define GEMM_BODY(...)                                                         \
  const int Kd = 1024;                                                         \
  const int nk = 32; /* 1024/32 */                                             \
  __shared__ bf16 As[4][256 * 32];                                             \
  __shared__ bf16 Bs[4][256 * 32];                                             \
  int tid = threadIdx.x;                                                       \
  int lane = tid & 63, wid = tid >> 6;                                         \
  int l15 = lane & 15, hi = lane >> 4;                                         \
  int wm = wid >> 2, wn = wid & 3;                                             \
  f32x4 acc[8][4];                                                             \
  _Pragma("unroll") for (int i = 0; i < 8; i++)                                \
      _Pragma("unroll") for (int j = 0; j < 4; j++)                            \
          acc[i][j] = (f32x4){0.f, 0.f, 0.f, 0.f};                             \
  auto stageA = [&](int slot, int kk) {                                        \
    const bf16* ab = Abase + kk * 32;                                          \
    _Pragma("unroll") for (int pass = 0; pass < 2; pass++) {                   \
      int p = pass * 512 + tid;                                                \
      int row = p >> 2;                                                        \
      int u = (p & 3) ^ ((row >> 1) & 3);                                      \
      gl16(ab + (size_t)row * Kd + u * 8, (char*)(&As[slot][0]) + p * 16);     \
    }                                                                          \
  };                                                                           \
  auto stageB = [&](int slot, int kk) {                                        \
    const bf16* bb = Bbase + kk * 32;                                          \
    _Pragma("unroll") for (int pass = 0; pass < 2; pass++) {                   \
      int p = pass * 512 + tid;                                                \
      int row = p >> 2;                                                        \
      int u = (p & 3) ^ ((row >> 1) & 3);                                      \
      gl16(bb + (size_t)row * Kd + u * 8, (char*)(&Bs[slot][0]) + p * 16);     \
    }                                                                          \
  };                                                                           \
  stageA(0, 0); stageB(0, 0);                                                  \
  stageA(1, 1); stageB(1, 1);                                                  \
  stageA(2, 2); stageB(2, 2);                                                  \
  asm volatile("s_waitcnt vmcnt(8)" ::: "memory");                             \
  SCHED0; __builtin_amdgcn_s_barrier(); SCHED0;                                \
  int sw = ((l15 >> 1) & 3) << 4;                                              \
  int arow0 = wm * 128 + l15;                                                  \
  int brow0 = wn * 64 + l15;                                                   \
  short8 a_cur[4], a_hi[4], b_cur[4], b_nxt[4];                                \
  _Pragma("unroll") for (int mf = 0; mf < 4; mf++)                             \
      a_cur[mf] = *(const short8*)((const char*)(&As[0][0]) +                  \
                                   (((arow0 + mf * 16) * 64 + hi * 16) ^ sw)); \
  _Pragma("unroll") for (int nf = 0; nf < 4; nf++)                             \
      b_cur[nf] = *(const short8*)((const char*)(&Bs[0][0]) +                  \
                                   (((brow0 + nf * 16) * 64 + hi * 16) ^ sw)); \
  _Pragma("unroll 2") for (int t = 0; t < nk; ++t) {                           \
    int slot = t & 3;                                                          \
    const char* Ab = (const char*)(&As[slot][0]);                              \
    /* ---- PHASE A: stage A(t+3); read A4-7(t); MFMA acc[0-3] ---- */         \
    if (t + 3 < nk) stageA((t + 3) & 3, t + 3);                                \
    _Pragma("unroll") for (int mf = 0; mf < 4; mf++)                           \
        a_hi[mf] = *(const short8*)(Ab +                                       \
            (((arow0 + 64 + mf * 16) * 64 + hi * 16) ^ sw));                   \
    SCHED0;                                                                    \
    __builtin_amdgcn_s_setprio(1);                                             \
    _Pragma("unroll") for (int mf = 0; mf < 4; mf++)                           \
        _Pragma("unroll") for (int nf = 0; nf < 4; nf++)                       \
            acc[mf][nf] = __builtin_amdgcn_mfma_f32_16x16x32_bf16(             \
                a_cur[mf], b_cur[nf], acc[mf][nf], 0, 0, 0);                   \
    __builtin_amdgcn_s_setprio(0);                                             \
    SCHED0;                                                                    \
    /* ---- PHASE B: stage B(t+3); vmcnt; barrier; read t+1; MFMA 4-7 ---- */  \
    if (t + 3 < nk) stageB((t + 3) & 3, t + 3);                                \
    if (t + 1 < nk) {                                                          \
      SCHED0;                                                                  \
      if (t + 3 < nk)      asm volatile("s_waitcnt vmcnt(8)" ::: "memory");    \
      else if (t + 2 < nk) asm volatile("s_waitcnt vmcnt(4)" ::: "memory");    \
      else                 asm volatile("s_waitcnt vmcnt(0)" ::: "memory");    \
      SCHED0; __builtin_amdgcn_s_barrier(); SCHED0;                            \
      const char* AbN = (const char*)(&As[(t + 1) & 3][0]);                    \
      const char* BbN = (const char*)(&Bs[(t + 1) & 3][0]);                    \
      _Pragma("unroll") for (int mf = 0; mf < 4; mf++)                         \
          a_cur[mf] = *(const short8*)(AbN +                                   \
              (((arow0 + mf * 16) * 64 + hi * 16) ^ sw));                      \
      _Pragma("unroll") for (int nf = 0; nf < 4; nf++)                         \
          b_nxt[nf] = *(const short8*)(BbN +                                   \
              (((brow0 + nf * 16) * 64 + hi * 16) ^ sw));                      \
      SCHED0;                                                                  \
    }                                                                          \
    __builtin_amdgcn_s_setprio(1);                                             \
    _Pragma("unroll") for (int mf = 0; mf < 4; mf++)                           \
        _Pragma("unroll") for (int nf = 0; nf < 4; nf++)                       \
            acc[mf + 4][nf] = __builtin_amdgcn_mfma_f32_16x16x32_bf16(         \
                a_hi[mf], b_cur[nf], acc[mf + 4][nf], 0, 0, 0);                \
    __builtin_amdgcn_s_setprio(0);                                             \
    SCHED0;                                                                    \
    if (t + 1 < nk) { __builtin_amdgcn_s_barrier(); SCHED0; }                  \
    _Pragma("unroll") for (int nf = 0; nf < 4; nf++) b_cur[nf] = b_nxt[nf];    \
  }                                                                            \
  __VA_ARGS__

__global__ __launch_bounds__(512, 2) void k_qkv_gemm(
    const bf16* __restrict__ X, const bf16* __restrict__ Wq,
    const bf16* __restrict__ Wk, const bf16* __restrict__ Wv,
    bf16* __restrict__ Q, bf16* __restrict__ K, bf16* __restrict__ V) {
  int bid = blockIdx.x;
  int wsel = bid >> 8;       // 0..2 : q,k,v
  int rem = bid & 255;
  int mt = rem & 63;
  int nt = rem >> 6;
  const bf16* W = (wsel == 0) ? Wq : (wsel == 1) ? Wk : Wv;
  bf16* Dst = (wsel == 0) ? Q : (wsel == 1) ? K : V;
  const bf16* Abase = X + (size_t)mt * 256 * 1024;
  const bf16* Bbase = W + (size_t)nt * 256 * 1024;
  GEMM_BODY({
    _Pragma("unroll") for (int mf = 0; mf < 8; mf++) {
      _Pragma("unroll") for (int r = 0; r < 4; r++) {
        int row = mt * 256 + wm * 128 + mf * 16 + hi * 4 + r;  // token
        int b = row >> 13;
        int tok = row & 8191;
        _Pragma("unroll") for (int nf = 0; nf < 4; nf++) {
          int col = nt * 256 + wn * 64 + nf * 16 + l15;        // channel
          int h = col >> 6;
          int d = col & 63;
          Dst[((size_t)(b * 16 + h) * 8192 + tok) * 64 + d] =
              __float2bfloat16(acc[mf][nf][r]);
        }
      }
    }
  })
}

__global__ __launch_bounds__(512, 2) void k_out_gemm(
    const bf16* __restrict__ A, const bf16* __restrict__ Wo,
    float* __restrict__ Out) {
  int bid = blockIdx.x;
  int mt = bid & 63;
  int nt = bid >> 6;
  const bf16* Abase = A + (size_t)mt * 256 * 1024;
  const bf16* Bbase = Wo + (size_t)nt * 256 * 1024;
  GEMM_BODY({
    _Pragma("unroll") for (int mf = 0; mf < 8; mf++) {
      _Pragma("unroll") for (int r = 0; r < 4; r++) {
        int row = mt * 256 + wm * 128 + mf * 16 + hi * 4 + r;
        _Pragma("unroll") for (int nf = 0; nf < 4; nf++) {
          int col = nt * 256 + wn * 64 + nf * 16 + l15;
          Out[(size_t)row * 1024 + col] = acc[mf][nf][r];
        }
      }
    }
  })
}

// ---------------- V transpose: [B,H,T,D] -> [B,H,D,T] ----------------
__global__ __launch_bounds__(256) void k_vtrans(const bf16* __restrict__ V,
                                                bf16* __restrict__ VT) {
  const int T = 8192;
  __shared__ bf16 tile[64][72];
  int bid = blockIdx.x;
  int tb = bid & 127;
  int bh = bid >> 7;
  int t0 = tb * 64;
  int tid = threadIdx.x;
  int r = tid >> 2, c4 = tid & 3;
  const bf16* src = V + ((size_t)bh * T + t0 + r) * 64 + c4 * 16;
  short8 a = *(const short8*)src;
  short8 b2 = *(const short8*)(src + 8);
#pragma unroll
  for (int e = 0; e < 8; e++) tile[r][c4 * 16 + e] = ((bf16*)&a)[e];
#pragma unroll
  for (int e = 0; e < 8; e++) tile[r][c4 * 16 + 8 + e] = ((bf16*)&b2)[e];
  __syncthreads();
  alignas(16) bf16 o[16];
#pragma unroll
  for (int e = 0; e < 16; e++) o[e] = tile[c4 * 16 + e][r];
  bf16* dst = VT + ((size_t)bh * 64 + r) * T + t0 + c4 * 16;
  *(short8*)dst = *(short8*)o;
  *(short8*)(dst + 8) = *((short8*)o + 1);
}

// ---------------- sliding-window attention ----------------
__global__ __launch_bounds__(256) void k_attn(
    const bf16* __restrict__ Q, const bf16* __restrict__ K,
    const bf16* __restrict__ VT, bf16* __restrict__ ATT) {
  const int T = 8192;
  __shared__ bf16 Ks[2][64 * 64];
  __shared__ bf16 Vs[2][64 * 64];  // V^T chunk: [d][j]
  __shared__ bf16 Ps[4][16 * 64];  // per-wave P
  int bid = blockIdx.x;
  int qt = bid & 127;
  int bh = bid >> 7;  // 0..31
  int b = bh >> 4, h = bh & 15;
  int tid = threadIdx.x;
  int lane = tid & 63, wid = tid >> 6;
  int l15 = lane & 15, hi = lane >> 4;
  int q0 = qt * 64;
  int qw = q0 + wid * 16;

  short8 bq[2];
  const bf16* qp = Q + ((size_t)bh * T + qw + l15) * 64 + hi * 8;
  bq[0] = *(const short8*)qp;
  bq[1] = *(const short8*)(qp + 32);

  const bf16* Kbh = K + (size_t)bh * T * 64;
  const bf16* Vbh = VT + (size_t)bh * 64 * T;

  auto stage = [&](int bb, int c0) {
#pragma unroll
    for (int pass = 0; pass < 2; pass++) {
      int p = pass * 256 + tid;
      int row = p >> 3;
      int u = (p & 7) ^ (row & 7);
      gl16(Kbh + ((size_t)(c0 + row)) * 64 + u * 8, (char*)(&Ks[bb][0]) + p * 16);
      gl16(Vbh + (size_t)row * T + c0 + u * 8, (char*)(&Vs[bb][0]) + p * 16);
    }
  };

  int cstart = q0 - 512; if (cstart < 0) cstart = 0;
  int nch = (q0 + 64 - cstart) >> 6;

  f32x4 oacc[4];
#pragma unroll
  for (int c = 0; c < 4; c++) oacc[c] = (f32x4){0.f, 0.f, 0.f, 0.f};
  float m = -1e30f, ssum = 0.f;

  stage(0, cstart);
  __syncthreads();
  int buf = 0;
  for (int ci = 0; ci < nch; ci++) {
    int c0 = cstart + (ci << 6);
    if (ci + 1 < nch) stage(buf ^ 1, c0 + 64);
    f32x4 sacc[4];
#pragma unroll
    for (int ks = 0; ks < 4; ks++) sacc[ks] = (f32x4){0.f, 0.f, 0.f, 0.f};
#pragma unroll
    for (int dh = 0; dh < 2; dh++) {
#pragma unroll
      for (int ks = 0; ks < 4; ks++) {
        int krow = ks * 16 + l15;
        int boff = ((krow * 64 + dh * 32 + hi * 8) * 2) ^ ((krow & 7) << 4);
        short8 ak = *(const short8*)((const char*)(&Ks[buf][0]) + boff);
        sacc[ks] = __builtin_amdgcn_mfma_f32_16x16x32_bf16(ak, bq[dh], sacc[ks], 0, 0, 0);
      }
    }
    int qg = qw + l15;
    float pv[4][4];
    float pmax = -1e30f;
#pragma unroll
    for (int ks = 0; ks < 4; ks++)
#pragma unroll
      for (int r = 0; r < 4; r++) {
        int jg = c0 + ks * 16 + hi * 4 + r;
        float s = sacc[ks][r] * 0.125f;
        bool ok = (jg <= qg) && (jg > qg - 512);
        s = ok ? s : -1e30f;
        pv[ks][r] = s;
        pmax = fmaxf(pmax, s);
      }
    pmax = fmaxf(pmax, __shfl_xor(pmax, 16));
    pmax = fmaxf(pmax, __shfl_xor(pmax, 32));
    float mnew = fmaxf(m, pmax);
    float corr = __expf(m - mnew);
    float psum = 0.f;
#pragma unroll
    for (int ks = 0; ks < 4; ks++)
#pragma unroll
      for (int r = 0; r < 4; r++) {
        float p = (pv[ks][r] > -1e29f) ? __expf(pv[ks][r] - mnew) : 0.f;
        pv[ks][r] = p;
        psum += p;
      }
    psum += __shfl_xor(psum, 16);
    psum += __shfl_xor(psum, 32);
    ssum = ssum * corr + psum;
    m = mnew;
#pragma unroll
    for (int r = 0; r < 4; r++) {
      float f = __shfl(corr, hi * 4 + r);
#pragma unroll
      for (int c = 0; c < 4; c++) oacc[c][r] *= f;
    }
#pragma unroll
    for (int ks = 0; ks < 4; ks++) {
      unsigned int lo = (unsigned)bfbits(pv[ks][0]) | ((unsigned)bfbits(pv[ks][1]) << 16);
      unsigned int hi2 = (unsigned)bfbits(pv[ks][2]) | ((unsigned)bfbits(pv[ks][3]) << 16);
      int j0 = ks * 16 + hi * 4;
      int a0 = ((l15 * 64 + j0) * 2) ^ ((l15 & 7) << 4);
      int a1 = ((l15 * 64 + j0 + 2) * 2) ^ ((l15 & 7) << 4);
      *(unsigned int*)((char*)(&Ps[wid][0]) + a0) = lo;
      *(unsigned int*)((char*)(&Ps[wid][0]) + a1) = hi2;
    }
    short8 ap[2];
#pragma unroll
    for (int js = 0; js < 2; js++) {
      int a = ((l15 * 64 + js * 32 + hi * 8) * 2) ^ ((l15 & 7) << 4);
      ap[js] = *(const short8*)((const char*)(&Ps[wid][0]) + a);
    }
#pragma unroll
    for (int js = 0; js < 2; js++)
#pragma unroll
      for (int c = 0; c < 4; c++) {
        int vrow = c * 16 + l15;
        int boff = ((vrow * 64 + js * 32 + hi * 8) * 2) ^ ((vrow & 7) << 4);
        short8 bv = *(const short8*)((const char*)(&Vs[buf][0]) + boff);
        oacc[c] = __builtin_amdgcn_mfma_f32_16x16x32_bf16(ap[js], bv, oacc[c], 0, 0, 0);
      }
    __syncthreads();
    buf ^= 1;
  }
  float inv = 1.f / ssum;
#pragma unroll
  for (int r = 0; r < 4; r++) {
    float f = __shfl(inv, hi * 4 + r);
    int tok = qw + hi * 4 + r;
    bf16* dst = ATT + ((size_t)b * 8192 + tok) * 1024 + h * 64;
#pragma unroll
    for (int c = 0; c < 4; c++)
      dst[c * 16 + l15] = __float2bfloat16(oacc[c][r] * f);
  }
}

extern "C" void kernel_launch(void* const* d_in, const int* in_sizes, int n_in,
                              void* d_out, int out_size, void* d_ws, size_t ws_size,
                              hipStream_t stream) {
  const float* x  = (const float*)d_in[0];
  const float* wq = (const float*)d_in[1];
  const float* wk = (const float*)d_in[2];
  const float* wv = (const float*)d_in[3];
  const float* wo = (const float*)d_in[4];
  float* out = (float*)d_out;

  char* ws = (char*)d_ws;
  const size_t SZ_X = (size_t)16384 * 1024 * 2;  // 32 MB bf16
  const size_t SZ_W = (size_t)1024 * 1024 * 2;   // 2 MB bf16
  size_t off = 0;
  bf16* xb  = (bf16*)(ws + off); off += SZ_X;
  bf16* wqb = (bf16*)(ws + off); off += SZ_W;
  bf16* wkb = (bf16*)(ws + off); off += SZ_W;
  bf16* wvb = (bf16*)(ws + off); off += SZ_W;
  bf16* wob = (bf16*)(ws + off); off += SZ_W;
  bf16* qb  = (bf16*)(ws + off); off += SZ_X;
  bf16* kb  = (bf16*)(ws + off); off += SZ_X;
  bf16* vb  = (bf16*)(ws + off); off += SZ_X;
  bf16* vtb = (bf16*)(ws + off); off += SZ_X;
  bf16* att = xb;  // alias: x_bf16 dead after QKV GEMM

  k_cvt<<<2048, 256, 0, stream>>>(x, xb, 16384 * 1024 / 8);
  k_cvt<<<512, 256, 0, stream>>>(wq, wqb, 1024 * 1024 / 8);
  k_cvt<<<512, 256, 0, stream>>>(wk, wkb, 1024 * 1024 / 8);
  k_cvt<<<512, 256, 0, stream>>>(wv, wvb, 1024 * 1024 / 8);
  k_cvt<<<512, 256, 0, stream>>>(wo, wob, 1024 * 1024 / 8);
  k_qkv_gemm<<<768, 512, 0, stream>>>(xb, wqb, wkb, wvb, qb, kb, vb);
  k_vtrans<<<4096, 256, 0, stream>>>(vb, vtb);
  k_attn<<<4096, 256, 0, stream>>>(qb, kb, vtb, att);
  k_out_gemm<<<256, 512, 0, stream>>>(att, wob, out);
}

// Round 6
// 309.254 us; speedup vs baseline: 1.1053x; 1.0037x over previous
//
#include <hip/hip_runtime.h>
#include <hip/hip_bf16.h>
#include <stdint.h>

typedef __attribute__((ext_vector_type(8))) short short8;
typedef __attribute__((ext_vector_type(4))) float f32x4;
typedef __hip_bfloat16 bf16;

#define AS1 __attribute__((address_space(1)))
#define AS3 __attribute__((address_space(3)))

__device__ __forceinline__ void gl16(const void* g, void* l) {
  __builtin_amdgcn_global_load_lds((const AS1 unsigned int*)g,
                                   (AS3 unsigned int*)l, 16, 0, 0);
}

__device__ __forceinline__ unsigned short bfbits(float x) {
  union { bf16 b; unsigned short u; } c; c.b = __float2bfloat16(x); return c.u;
}

#define SCHED0 __builtin_amdgcn_sched_barrier(0)

// ---------------- fp32 -> bf16 convert (vectorized) ----------------
__global__ __launch_bounds__(256) void k_cvt(const float* __restrict__ src,
                                             bf16* __restrict__ dst, int n8) {
  int i = blockIdx.x * blockDim.x + threadIdx.x;
  int stride = gridDim.x * blockDim.x;
  for (; i < n8; i += stride) {
    const float4* p = (const float4*)src + (size_t)i * 2;
    float4 a = p[0], b = p[1];
    bf16 tmp[8];
    tmp[0] = __float2bfloat16(a.x); tmp[1] = __float2bfloat16(a.y);
    tmp[2] = __float2bfloat16(a.z); tmp[3] = __float2bfloat16(a.w);
    tmp[4] = __float2bfloat16(b.x); tmp[5] = __float2bfloat16(b.y);
    tmp[6] = __float2bfloat16(b.z); tmp[7] = __float2bfloat16(b.w);
    *(short8*)(dst + (size_t)i * 8) = *(short8*)tmp;
  }
}

// ======== 256x256 GEMM, BK=64, 8 waves (2Mx4N), m201-style 4-phase =========
// LDS: A/B each [2buf][2 K-halves][256x32] = 128 KB. Half-tile = [256x32]
// (16 KB, 2 gl16/thread). Per phase: {ds_read subtile || stage 1 half-tile
// -> barrier -> lgkmcnt(0)+sched0 -> setprio 16 MFMA -> barrier}. Counted
// vmcnt(4) at phases 1 and 3 only (2 half-tiles in flight, never 0 mid-loop).
// Staging order per tile t: ph0 A-kh0(t+1), ph1 B-kh0(t+1), ph2 A-kh1(t+1),
// ph3 B-kh1(t+1). WAR: each stage is >=2 barriers after its region's death.

#define GEMM_BODY(...)                                                         \
  const int nk = 16; /* 1024/64 */                                             \
  __shared__ bf16 As[2][2][256 * 32];                                          \
  __shared__ bf16 Bs[2][2][256 * 32];                                          \
  int tid = threadIdx.x;                                                       \
  int lane = tid & 63, wid = tid >> 6;                                         \
  int l15 = lane & 15, hi = lane >> 4;                                         \
  int wm = wid >> 2, wn = wid & 3;                                             \
  f32x4 acc[8][4];                                                             \
  _Pragma("unroll") for (int i = 0; i < 8; i++)                                \
      _Pragma("unroll") for (int j = 0; j < 4; j++)                            \
          acc[i][j] = (f32x4){0.f, 0.f, 0.f, 0.f};                             \
  auto stage_half = [&](char* dst, const bf16* src) {                          \
    _Pragma("unroll") for (int pass = 0; pass < 2; pass++) {                   \
      int c = pass * 512 + tid;  /* 1024 x 16B = 16 KB */                      \
      int row = c >> 2;                                                        \
      int u = (c & 3) ^ ((row >> 1) & 3);  /* inverse swizzle (rule 21) */     \
      gl16(src + (size_t)row * 1024 + u * 8, dst + c * 16);                    \
    }                                                                          \
  };                                                                           \
  /* prologue: tile 0, all 4 half-tiles; vmcnt(4) -> A0,B0 landed */           \
  stage_half((char*)&As[0][0][0], Abase);                                      \
  stage_half((char*)&Bs[0][0][0], Bbase);                                      \
  stage_half((char*)&As[0][1][0], Abase + 32);                                 \
  stage_half((char*)&Bs[0][1][0], Bbase + 32);                                 \
  asm volatile("s_waitcnt vmcnt(4)" ::: "memory");                             \
  SCHED0; __builtin_amdgcn_s_barrier(); SCHED0;                                \
  int sw = ((l15 >> 1) & 3) << 4;                                              \
  int arow = wm * 128 + l15;                                                   \
  int brow = wn * 64 + l15;                                                    \
  short8 af[4], bfr[4];                                                        \
  _Pragma("unroll 2") for (int t = 0; t < nk; ++t) {                           \
    int cb = t & 1, nb = cb ^ 1;                                               \
    const char* A0 = (const char*)&As[cb][0][0];                               \
    const char* A1 = (const char*)&As[cb][1][0];                               \
    const char* B0 = (const char*)&Bs[cb][0][0];                               \
    const char* B1 = (const char*)&Bs[cb][1][0];                               \
    const bf16* an = Abase + (t + 1) * 64;                                     \
    const bf16* bn = Bbase + (t + 1) * 64;                                     \
    /* ---- phase 0: B(kh0) + A(mf0-3,kh0); stage A-kh0(t+1) ---- */           \
    _Pragma("unroll") for (int nf = 0; nf < 4; nf++)                           \
        bfr[nf] = *(const short8*)(B0 +                                        \
            (((brow + nf * 16) * 64 + hi * 16) ^ sw));                         \
    _Pragma("unroll") for (int mf = 0; mf < 4; mf++)                           \
        af[mf] = *(const short8*)(A0 +                                         \
            (((arow + mf * 16) * 64 + hi * 16) ^ sw));                         \
    if (t + 1 < nk) stage_half((char*)&As[nb][0][0], an);                      \
    SCHED0; __builtin_amdgcn_s_barrier();                                      \
    asm volatile("s_waitcnt lgkmcnt(0)" ::: "memory"); SCHED0;                 \
    __builtin_amdgcn_s_setprio(1);                                             \
    _Pragma("unroll") for (int mf = 0; mf < 4; mf++)                           \
        _Pragma("unroll") for (int nf = 0; nf < 4; nf++)                       \
            acc[mf][nf] = __builtin_amdgcn_mfma_f32_16x16x32_bf16(             \
                af[mf], bfr[nf], acc[mf][nf], 0, 0, 0);                        \
    __builtin_amdgcn_s_setprio(0);                                             \
    SCHED0; __builtin_amdgcn_s_barrier(); SCHED0;                              \
    /* ---- phase 1: A(mf4-7,kh0); stage B-kh0(t+1); vmcnt ---- */             \
    _Pragma("unroll") for (int mf = 0; mf < 4; mf++)                           \
        af[mf] = *(const short8*)(A0 +                                         \
            (((arow + 64 + mf * 16) * 64 + hi * 16) ^ sw));                    \
    if (t + 1 < nk) stage_half((char*)&Bs[nb][0][0], bn);                      \
    SCHED0;                                                                    \
    if (t + 1 < nk) asm volatile("s_waitcnt vmcnt(4)" ::: "memory");           \
    else            asm volatile("s_waitcnt vmcnt(0)" ::: "memory");           \
    SCHED0; __builtin_amdgcn_s_barrier();                                      \
    asm volatile("s_waitcnt lgkmcnt(0)" ::: "memory"); SCHED0;                 \
    __builtin_amdgcn_s_setprio(1);                                             \
    _Pragma("unroll") for (int mf = 0; mf < 4; mf++)                           \
        _Pragma("unroll") for (int nf = 0; nf < 4; nf++)                       \
            acc[mf + 4][nf] = __builtin_amdgcn_mfma_f32_16x16x32_bf16(         \
                af[mf], bfr[nf], acc[mf + 4][nf], 0, 0, 0);                    \
    __builtin_amdgcn_s_setprio(0);                                             \
    SCHED0; __builtin_amdgcn_s_barrier(); SCHED0;                              \
    /* ---- phase 2: B(kh1) + A(mf0-3,kh1); stage A-kh1(t+1) ---- */           \
    _Pragma("unroll") for (int nf = 0; nf < 4; nf++)                           \
        bfr[nf] = *(const short8*)(B1 +                                        \
            (((brow + nf * 16) * 64 + hi * 16) ^ sw));                         \
    _Pragma("unroll") for (int mf = 0; mf < 4; mf++)                           \
        af[mf] = *(const short8*)(A1 +                                         \
            (((arow + mf * 16) * 64 + hi * 16) ^ sw));                         \
    if (t + 1 < nk) stage_half((char*)&As[nb][1][0], an + 32);                 \
    SCHED0; __builtin_amdgcn_s_barrier();                                      \
    asm volatile("s_waitcnt lgkmcnt(0)" ::: "memory"); SCHED0;                 \
    __builtin_amdgcn_s_setprio(1);                                             \
    _Pragma("unroll") for (int mf = 0; mf < 4; mf++)                           \
        _Pragma("unroll") for (int nf = 0; nf < 4; nf++)                       \
            acc[mf][nf] = __builtin_amdgcn_mfma_f32_16x16x32_bf16(             \
                af[mf], bfr[nf], acc[mf][nf], 0, 0, 0);                        \
    __builtin_amdgcn_s_setprio(0);                                             \
    SCHED0; __builtin_amdgcn_s_barrier(); SCHED0;                              \
    /* ---- phase 3: A(mf4-7,kh1); stage B-kh1(t+1); vmcnt ---- */             \
    _Pragma("unroll") for (int mf = 0; mf < 4; mf++)                           \
        af[mf] = *(const short8*)(A1 +                                         \
            (((arow + 64 + mf * 16) * 64 + hi * 16) ^ sw));                    \
    if (t + 1 < nk) {                                                          \
      stage_half((char*)&Bs[nb][1][0], bn + 32);                               \
      SCHED0;                                                                  \
      asm volatile("s_waitcnt vmcnt(4)" ::: "memory");                         \
    }                                                                          \
    SCHED0; __builtin_amdgcn_s_barrier();                                      \
    asm volatile("s_waitcnt lgkmcnt(0)" ::: "memory"); SCHED0;                 \
    __builtin_amdgcn_s_setprio(1);                                             \
    _Pragma("unroll") for (int mf = 0; mf < 4; mf++)                           \
        _Pragma("unroll") for (int nf = 0; nf < 4; nf++)                       \
            acc[mf + 4][nf] = __builtin_amdgcn_mfma_f32_16x16x32_bf16(         \
                af[mf], bfr[nf], acc[mf + 4][nf], 0, 0, 0);                    \
    __builtin_amdgcn_s_setprio(0);                                             \
    SCHED0; __builtin_amdgcn_s_barrier(); SCHED0;                              \
  }                                                                            \
  __VA_ARGS__

__global__ __launch_bounds__(512, 2) void k_qkv_gemm(
    const bf16* __restrict__ X, const bf16* __restrict__ Wq,
    const bf16* __restrict__ Wk, const bf16* __restrict__ Wv,
    bf16* __restrict__ Q, bf16* __restrict__ K, bf16* __restrict__ V) {
  int bid = blockIdx.x;
  int wsel = bid >> 8;       // 0..2 : q,k,v
  int rem = bid & 255;
  int mt = rem & 63;
  int nt = rem >> 6;
  const bf16* W = (wsel == 0) ? Wq : (wsel == 1) ? Wk : Wv;
  bf16* Dst = (wsel == 0) ? Q : (wsel == 1) ? K : V;
  const bf16* Abase = X + (size_t)mt * 256 * 1024;
  const bf16* Bbase = W + (size_t)nt * 256 * 1024;
  GEMM_BODY({
    _Pragma("unroll") for (int mf = 0; mf < 8; mf++) {
      _Pragma("unroll") for (int r = 0; r < 4; r++) {
        int row = mt * 256 + wm * 128 + mf * 16 + hi * 4 + r;  // token
        int b = row >> 13;
        int tok = row & 8191;
        _Pragma("unroll") for (int nf = 0; nf < 4; nf++) {
          int col = nt * 256 + wn * 64 + nf * 16 + l15;        // channel
          int h = col >> 6;
          int d = col & 63;
          Dst[((size_t)(b * 16 + h) * 8192 + tok) * 64 + d] =
              __float2bfloat16(acc[mf][nf][r]);
        }
      }
    }
  })
}

__global__ __launch_bounds__(512, 2) void k_out_gemm(
    const bf16* __restrict__ A, const bf16* __restrict__ Wo,
    float* __restrict__ Out) {
  int bid = blockIdx.x;
  int mt = bid & 63;
  int nt = bid >> 6;
  const bf16* Abase = A + (size_t)mt * 256 * 1024;
  const bf16* Bbase = Wo + (size_t)nt * 256 * 1024;
  GEMM_BODY({
    _Pragma("unroll") for (int mf = 0; mf < 8; mf++) {
      _Pragma("unroll") for (int r = 0; r < 4; r++) {
        int row = mt * 256 + wm * 128 + mf * 16 + hi * 4 + r;
        _Pragma("unroll") for (int nf = 0; nf < 4; nf++) {
          int col = nt * 256 + wn * 64 + nf * 16 + l15;
          Out[(size_t)row * 1024 + col] = acc[mf][nf][r];
        }
      }
    }
  })
}

// ---------------- V transpose: [B,H,T,D] -> [B,H,D,T] ----------------
__global__ __launch_bounds__(256) void k_vtrans(const bf16* __restrict__ V,
                                                bf16* __restrict__ VT) {
  const int T = 8192;
  __shared__ bf16 tile[64][72];
  int bid = blockIdx.x;
  int tb = bid & 127;
  int bh = bid >> 7;
  int t0 = tb * 64;
  int tid = threadIdx.x;
  int r = tid >> 2, c4 = tid & 3;
  const bf16* src = V + ((size_t)bh * T + t0 + r) * 64 + c4 * 16;
  short8 a = *(const short8*)src;
  short8 b2 = *(const short8*)(src + 8);
#pragma unroll
  for (int e = 0; e < 8; e++) tile[r][c4 * 16 + e] = ((bf16*)&a)[e];
#pragma unroll
  for (int e = 0; e < 8; e++) tile[r][c4 * 16 + 8 + e] = ((bf16*)&b2)[e];
  __syncthreads();
  alignas(16) bf16 o[16];
#pragma unroll
  for (int e = 0; e < 16; e++) o[e] = tile[c4 * 16 + e][r];
  bf16* dst = VT + ((size_t)bh * 64 + r) * T + t0 + c4 * 16;
  *(short8*)dst = *(short8*)o;
  *(short8*)(dst + 8) = *((short8*)o + 1);
}

// ---------------- sliding-window attention (Q-tile 128, 8 waves) -----------
__global__ __launch_bounds__(512) void k_attn(
    const bf16* __restrict__ Q, const bf16* __restrict__ K,
    const bf16* __restrict__ VT, bf16* __restrict__ ATT) {
  const int T = 8192;
  __shared__ bf16 Ks[2][64 * 64];
  __shared__ bf16 Vs[2][64 * 64];  // V^T chunk: [d][j]
  __shared__ bf16 Ps[8][16 * 64];  // per-wave P
  int bid = blockIdx.x;
  int qt = bid & 63;
  int bh = bid >> 6;  // 0..31
  int b = bh >> 4, h = bh & 15;
  int tid = threadIdx.x;
  int lane = tid & 63, wid = tid >> 6;
  int l15 = lane & 15, hi = lane >> 4;
  int q0 = qt * 128;
  int qw = q0 + wid * 16;

  short8 bq[2];
  const bf16* qp = Q + ((size_t)bh * T + qw + l15) * 64 + hi * 8;
  bq[0] = *(const short8*)qp;
  bq[1] = *(const short8*)(qp + 32);

  const bf16* Kbh = K + (size_t)bh * T * 64;
  const bf16* Vbh = VT + (size_t)bh * 64 * T;

  auto stage = [&](int bb, int c0) {
    int p = tid;  // 512 threads x 16B = 8KB (one buffer)
    int row = p >> 3;
    int u = (p & 7) ^ (row & 7);
    gl16(Kbh + ((size_t)(c0 + row)) * 64 + u * 8, (char*)(&Ks[bb][0]) + p * 16);
    gl16(Vbh + (size_t)row * T + c0 + u * 8, (char*)(&Vs[bb][0]) + p * 16);
  };

  int cstart = q0 - 512; if (cstart < 0) cstart = 0;
  int nch = (q0 + 128 - cstart) >> 6;

  f32x4 oacc[4];
#pragma unroll
  for (int c = 0; c < 4; c++) oacc[c] = (f32x4){0.f, 0.f, 0.f, 0.f};
  float m = -1e30f, ssum = 0.f;

  stage(0, cstart);
  __syncthreads();
  int buf = 0;
  for (int ci = 0; ci < nch; ci++) {
    int c0 = cstart + (ci << 6);
    if (ci + 1 < nch) stage(buf ^ 1, c0 + 64);
    f32x4 sacc[4];
#pragma unroll
    for (int ks = 0; ks < 4; ks++) sacc[ks] = (f32x4){0.f, 0.f, 0.f, 0.f};
#pragma unroll
    for (int dh = 0; dh < 2; dh++) {
#pragma unroll
      for (int ks = 0; ks < 4; ks++) {
        int krow = ks * 16 + l15;
        int boff = ((krow * 64 + dh * 32 + hi * 8) * 2) ^ ((krow & 7) << 4);
        short8 ak = *(const short8*)((const char*)(&Ks[buf][0]) + boff);
        sacc[ks] = __builtin_amdgcn_mfma_f32_16x16x32_bf16(ak, bq[dh], sacc[ks], 0, 0, 0);
      }
    }
    int qg = qw + l15;
    float pv[4][4];
    float pmax = -1e30f;
#pragma unroll
    for (int ks = 0; ks < 4; ks++)
#pragma unroll
      for (int r = 0; r < 4; r++) {
        int jg = c0 + ks * 16 + hi * 4 + r;
        float s = sacc[ks][r] * 0.125f;
        bool ok = (jg <= qg) && (jg > qg - 512);
        s = ok ? s : -1e30f;
        pv[ks][r] = s;
        pmax = fmaxf(pmax, s);
      }
    pmax = fmaxf(pmax, __shfl_xor(pmax, 16));
    pmax = fmaxf(pmax, __shfl_xor(pmax, 32));
    float mnew = fmaxf(m, pmax);
    float corr = __expf(m - mnew);
    float psum = 0.f;
#pragma unroll
    for (int ks = 0; ks < 4; ks++)
#pragma unroll
      for (int r = 0; r < 4; r++) {
        float p = (pv[ks][r] > -1e29f) ? __expf(pv[ks][r] - mnew) : 0.f;
        pv[ks][r] = p;
        psum += p;
      }
    psum += __shfl_xor(psum, 16);
    psum += __shfl_xor(psum, 32);
    ssum = ssum * corr + psum;
    m = mnew;
#pragma unroll
    for (int r = 0; r < 4; r++) {
      float f = __shfl(corr, hi * 4 + r);
#pragma unroll
      for (int c = 0; c < 4; c++) oacc[c][r] *= f;
    }
#pragma unroll
    for (int ks = 0; ks < 4; ks++) {
      unsigned int lo = (unsigned)bfbits(pv[ks][0]) | ((unsigned)bfbits(pv[ks][1]) << 16);
      unsigned int hi2 = (unsigned)bfbits(pv[ks][2]) | ((unsigned)bfbits(pv[ks][3]) << 16);
      int j0 = ks * 16 + hi * 4;
      int a0 = ((l15 * 64 + j0) * 2) ^ ((l15 & 7) << 4);
      int a1 = ((l15 * 64 + j0 + 2) * 2) ^ ((l15 & 7) << 4);
      *(unsigned int*)((char*)(&Ps[wid][0]) + a0) = lo;
      *(unsigned int*)((char*)(&Ps[wid][0]) + a1) = hi2;
    }
    short8 ap[2];
#pragma unroll
    for (int js = 0; js < 2; js++) {
      int a = ((l15 * 64 + js * 32 + hi * 8) * 2) ^ ((l15 & 7) << 4);
      ap[js] = *(const short8*)((const char*)(&Ps[wid][0]) + a);
    }
#pragma unroll
    for (int js = 0; js < 2; js++)
#pragma unroll
      for (int c = 0; c < 4; c++) {
        int vrow = c * 16 + l15;
        int boff = ((vrow * 64 + js * 32 + hi * 8) * 2) ^ ((vrow & 7) << 4);
        short8 bv = *(const short8*)((const char*)(&Vs[buf][0]) + boff);
        oacc[c] = __builtin_amdgcn_mfma_f32_16x16x32_bf16(ap[js], bv, oacc[c], 0, 0, 0);
      }
    __syncthreads();
    buf ^= 1;
  }
  float inv = 1.f / ssum;
#pragma unroll
  for (int r = 0; r < 4; r++) {
    float f = __shfl(inv, hi * 4 + r);
    int tok = qw + hi * 4 + r;
    bf16* dst = ATT + ((size_t)b * 8192 + tok) * 1024 + h * 64;
#pragma unroll
    for (int c = 0; c < 4; c++)
      dst[c * 16 + l15] = __float2bfloat16(oacc[c][r] * f);
  }
}

extern "C" void kernel_launch(void* const* d_in, const int* in_sizes, int n_in,
                              void* d_out, int out_size, void* d_ws, size_t ws_size,
                              hipStream_t stream) {
  const float* x  = (const float*)d_in[0];
  const float* wq = (const float*)d_in[1];
  const float* wk = (const float*)d_in[2];
  const float* wv = (const float*)d_in[3];
  const float* wo = (const float*)d_in[4];
  float* out = (float*)d_out;

  char* ws = (char*)d_ws;
  const size_t SZ_X = (size_t)16384 * 1024 * 2;  // 32 MB bf16
  const size_t SZ_W = (size_t)1024 * 1024 * 2;   // 2 MB bf16
  size_t off = 0;
  bf16* xb  = (bf16*)(ws + off); off += SZ_X;
  bf16* wqb = (bf16*)(ws + off); off += SZ_W;
  bf16* wkb = (bf16*)(ws + off); off += SZ_W;
  bf16* wvb = (bf16*)(ws + off); off += SZ_W;
  bf16* wob = (bf16*)(ws + off); off += SZ_W;
  bf16* qb  = (bf16*)(ws + off); off += SZ_X;
  bf16* kb  = (bf16*)(ws + off); off += SZ_X;
  bf16* vb  = (bf16*)(ws + off); off += SZ_X;
  bf16* vtb = (bf16*)(ws + off); off += SZ_X;
  bf16* att = xb;  // alias: x_bf16 dead after QKV GEMM

  k_cvt<<<2048, 256, 0, stream>>>(x, xb, 16384 * 1024 / 8);
  k_cvt<<<512, 256, 0, stream>>>(wq, wqb, 1024 * 1024 / 8);
  k_cvt<<<512, 256, 0, stream>>>(wk, wkb, 1024 * 1024 / 8);
  k_cvt<<<512, 256, 0, stream>>>(wv, wvb, 1024 * 1024 / 8);
  k_cvt<<<512, 256, 0, stream>>>(wo, wob, 1024 * 1024 / 8);
  k_qkv_gemm<<<768, 512, 0, stream>>>(xb, wqb, wkb, wvb, qb, kb, vb);
  k_vtrans<<<4096, 256, 0, stream>>>(vb, vtb);
  k_attn<<<2048, 512, 0, stream>>>(qb, kb, vtb, att);
  k_out_gemm<<<256, 512, 0, stream>>>(att, wob, out);
}